// Round 9
// baseline (677.472 us; speedup 1.0000x reference)
//
#include <hip/hip_runtime.h>
#include <cmath>

typedef short  short8 __attribute__((ext_vector_type(8)));
typedef float  f32x4  __attribute__((ext_vector_type(4)));
typedef unsigned short us8 __attribute__((ext_vector_type(8)));
typedef unsigned short us4 __attribute__((ext_vector_type(4)));

constexpr int kHW = 65536;           // 256*256
constexpr int kP  = 262144;          // 4 * kHW total pixels

__device__ __forceinline__ unsigned short f2bf(float x) {
  unsigned u = __builtin_bit_cast(unsigned, x);
  u += 0x7fffu + ((u >> 16) & 1u);
  return (unsigned short)(u >> 16);
}
__device__ __forceinline__ float bf2f(unsigned short h) {
  unsigned u = ((unsigned)h) << 16;
  return __builtin_bit_cast(float, u);
}
__device__ __forceinline__ void split2(float v, unsigned short& h, unsigned short& l) {
  unsigned short hh = f2bf(v);
  h = hh;
  l = f2bf(v - bf2f(hh));
}

// ---------------- bias table: bias_tab[h][i][j], h<6, i,j<64 ----------------
__global__ void bias_kernel(const float* __restrict__ w1, const float* __restrict__ b1,
                            const float* __restrict__ w2, const float* __restrict__ b2,
                            float* __restrict__ bias_tab) {
  int i = blockIdx.x;
  int j = threadIdx.x;
  float dy = (float)((i >> 3) - (j >> 3));
  float dx = (float)((i & 7) - (j & 7));
  float r0 = copysignf(log1pf(fabsf(dy)), dy);
  float r1 = copysignf(log1pf(fabsf(dx)), dx);
  float acc[6];
#pragma unroll
  for (int h = 0; h < 6; ++h) acc[h] = b2[h];
  for (int t = 0; t < 256; ++t) {
    float hv = fmaf(r0, w1[t], fmaf(r1, w1[256 + t], b1[t]));
    hv = fmaxf(hv, 0.f);
#pragma unroll
    for (int h = 0; h < 6; ++h) acc[h] = fmaf(hv, w2[t * 6 + h], acc[h]);
  }
#pragma unroll
  for (int h = 0; h < 6; ++h) bias_tab[h * 4096 + i * 64 + j] = acc[h];
}

// ---------------- weight prep: fp32 -> bf16 hi/lo planes ---------------------
__global__ void prep_weights(const float* __restrict__ qk_w, const float* __restrict__ v_w,
                             const float* __restrict__ c1w, const float* __restrict__ c2w,
                             const float* __restrict__ pjw,
                             unsigned short* __restrict__ Wqh, unsigned short* __restrict__ Wql,
                             unsigned short* __restrict__ W1h,
                             unsigned short* __restrict__ W2h,
                             unsigned short* __restrict__ Wph, unsigned short* __restrict__ Wpl) {
  int i = blockIdx.x * 256 + threadIdx.x;
  if (i < 27648) {
    float v = (i < 18432) ? qk_w[i] : v_w[i - 18432];
    split2(v, Wqh[i], Wql[i]);
  }
  if (i < 82944) {
    int dlt = i / 9216;
    int oc  = (i / 96) % 96;
    int ic  = i % 96;
    int src = (oc * 96 + ic) * 9 + dlt;
    W1h[i] = f2bf(c1w[src]);
    W2h[i] = f2bf(c2w[src]);
  }
  if (i < 9216) split2(pjw[i], Wph[i], Wpl[i]);
}

// ---------------- X: NCHW fp32 -> NHWC bf16 (hi only) -----------------------
__global__ __launch_bounds__(256) void split_x(const float* __restrict__ X,
                                               unsigned short* __restrict__ Xh) {
  __shared__ float tile[96][65];
  int t = threadIdx.x;
  size_t p0 = (size_t)blockIdx.x * 64;
  int b = (int)(p0 >> 16), pix = (int)(p0 & 65535);
  const float* xb = X + (size_t)b * 96 * kHW + pix;
#pragma unroll
  for (int i = 0; i < 24; ++i) {
    int ic = (t >> 6) + i * 4;
    tile[ic][t & 63] = xb[(size_t)ic * kHW + (t & 63)];
  }
  __syncthreads();
  int px = t >> 2;
  size_t outbase = (p0 + px) * 96;
#pragma unroll
  for (int cc = 0; cc < 3; ++cc) {
    int c = (t & 3) + cc * 4;
    us8 h8;
#pragma unroll
    for (int j = 0; j < 8; ++j) h8[j] = f2bf(tile[c * 8 + j][px]);
    *(us8*)(Xh + outbase + c * 8) = h8;
  }
}

// ---------------- merged QKV GEMM: X read once, B-frags in regs -------------
__global__ __launch_bounds__(256, 2) void qkv_gemm(
    const unsigned short* __restrict__ Wqh, const unsigned short* __restrict__ Wql,
    const unsigned short* __restrict__ Xh,
    const float* __restrict__ qk_b, const float* __restrict__ v_b,
    unsigned short* __restrict__ Qp, unsigned short* __restrict__ Kp,
    unsigned short* __restrict__ Vr) {
  int t = threadIdx.x, wv = t >> 6, lane = t & 63;
  size_t px0 = (size_t)blockIdx.x * 256 + wv * 64;
  int col = lane & 15, g = lane >> 4;

  const char* bH = (const char*)Xh + ((px0 + col) * 96 + g * 8) * 2;
  short8 Bh[3][4];
#pragma unroll
  for (int ks = 0; ks < 3; ++ks)
#pragma unroll
    for (int nf = 0; nf < 4; ++nf)
      Bh[ks][nf] = *(const short8*)(bH + (size_t)(nf * 16 * 96 + ks * 32) * 2);

#pragma unroll 1
  for (int z = 0; z < 3; ++z) {
    f32x4 acc[6][4];
#pragma unroll
    for (int m = 0; m < 6; ++m)
#pragma unroll
      for (int n = 0; n < 4; ++n) acc[m][n] = (f32x4)0.f;
    const char* aH = (const char*)(Wqh + z * 9216) + (size_t)(col * 96 + g * 8) * 2;
    const char* aL = (const char*)(Wql + z * 9216) + (size_t)(col * 96 + g * 8) * 2;
#pragma unroll
    for (int ks = 0; ks < 3; ++ks) {
      short8 Ah[6], Al[6];
#pragma unroll
      for (int mf = 0; mf < 6; ++mf) {
        Ah[mf] = *(const short8*)(aH + (size_t)(mf * 16 * 96 + ks * 32) * 2);
        Al[mf] = *(const short8*)(aL + (size_t)(mf * 16 * 96 + ks * 32) * 2);
      }
#pragma unroll
      for (int mf = 0; mf < 6; ++mf)
#pragma unroll
        for (int nf = 0; nf < 4; ++nf) {
          acc[mf][nf] = __builtin_amdgcn_mfma_f32_16x16x32_bf16(Ah[mf], Bh[ks][nf], acc[mf][nf], 0, 0, 0);
          acc[mf][nf] = __builtin_amdgcn_mfma_f32_16x16x32_bf16(Al[mf], Bh[ks][nf], acc[mf][nf], 0, 0, 0);
        }
    }
    const float* bias = (z == 0) ? qk_b : (z == 1 ? qk_b + 96 : v_b);
    float scale = (z == 0) ? 0.25f : 1.f;
#pragma unroll
    for (int mf = 0; mf < 6; ++mf) {
      int oc0 = mf * 16 + g * 4;
      f32x4 bv;
#pragma unroll
      for (int r = 0; r < 4; ++r) bv[r] = bias[oc0 + r];
#pragma unroll
      for (int nf = 0; nf < 4; ++nf) {
        size_t p = px0 + nf * 16 + col;
        f32x4 v = (acc[mf][nf] + bv) * scale;
        us4 o;
#pragma unroll
        for (int r = 0; r < 4; ++r) o[r] = f2bf(v[r]);
        if (z == 0)      *(us4*)(Qp + ((size_t)mf * kP + p) * 16 + g * 4) = o;
        else if (z == 1) *(us4*)(Kp + ((size_t)mf * kP + p) * 16 + g * 4) = o;
        else             *(us4*)(Vr + p * 96 + oc0) = o;
      }
    }
  }
}

// ---------------- attention: Q/K head-planar, V from row buffer -------------
__global__ __launch_bounds__(256) void attn_kernel(
    const unsigned short* __restrict__ Qp, const unsigned short* __restrict__ Kp,
    const unsigned short* __restrict__ Vr, const float* __restrict__ bias_tab,
    float* __restrict__ out) {
  __shared__ float bs[64 * 65];
  __shared__ float4 kls[4][4][64];
  __shared__ float4 vls[4][4][64];
  int t = threadIdx.x;
  int wv = t >> 6, lane = t & 63;
  int h = blockIdx.y;
  int wid = blockIdx.x * 4 + wv;
  int b = wid >> 10, wy = (wid >> 5) & 31, wx = wid & 31;
  size_t p = ((size_t)b << 16) + (size_t)(wy * 8 + (lane >> 3)) * 256 + wx * 8 + (lane & 7);
  size_t base = ((size_t)h * kP + p) * 16;
  us8 q0 = *(const us8*)(Qp + base), q1 = *(const us8*)(Qp + base + 8);
  us8 k0 = *(const us8*)(Kp + base), k1 = *(const us8*)(Kp + base + 8);
  size_t vbase = p * 96 + h * 16;
  us8 v0 = *(const us8*)(Vr + vbase), v1 = *(const us8*)(Vr + vbase + 8);
  float q[16];
#pragma unroll
  for (int d = 0; d < 8; ++d) {
    q[d]     = bf2f(q0[d]);
    q[8 + d] = bf2f(q1[d]);
  }
  kls[wv][0][lane] = make_float4(bf2f(k0[0]), bf2f(k0[1]), bf2f(k0[2]), bf2f(k0[3]));
  kls[wv][1][lane] = make_float4(bf2f(k0[4]), bf2f(k0[5]), bf2f(k0[6]), bf2f(k0[7]));
  kls[wv][2][lane] = make_float4(bf2f(k1[0]), bf2f(k1[1]), bf2f(k1[2]), bf2f(k1[3]));
  kls[wv][3][lane] = make_float4(bf2f(k1[4]), bf2f(k1[5]), bf2f(k1[6]), bf2f(k1[7]));
  vls[wv][0][lane] = make_float4(bf2f(v0[0]), bf2f(v0[1]), bf2f(v0[2]), bf2f(v0[3]));
  vls[wv][1][lane] = make_float4(bf2f(v0[4]), bf2f(v0[5]), bf2f(v0[6]), bf2f(v0[7]));
  vls[wv][2][lane] = make_float4(bf2f(v1[0]), bf2f(v1[1]), bf2f(v1[2]), bf2f(v1[3]));
  vls[wv][3][lane] = make_float4(bf2f(v1[4]), bf2f(v1[5]), bf2f(v1[6]), bf2f(v1[7]));
  {
    const float* bp = bias_tab + h * 4096;
#pragma unroll
    for (int r0 = 0; r0 < 16; ++r0) {
      int r = wv * 16 + r0;
      bs[r * 65 + lane] = bp[r * 64 + lane];
    }
  }
  __syncthreads();

  const float* brow = bs + lane * 65;
  float s[64];
#pragma unroll
  for (int j = 0; j < 64; ++j) {
    float kk[16];
    *(float4*)&kk[0]  = kls[wv][0][j];
    *(float4*)&kk[4]  = kls[wv][1][j];
    *(float4*)&kk[8]  = kls[wv][2][j];
    *(float4*)&kk[12] = kls[wv][3][j];
    float dot = brow[j];
#pragma unroll
    for (int d = 0; d < 16; ++d) dot = fmaf(q[d], kk[d], dot);
    s[j] = dot;
  }
  float m = s[0];
#pragma unroll
  for (int j = 1; j < 64; ++j) m = fmaxf(m, s[j]);
  float sum = 0.f;
#pragma unroll
  for (int j = 0; j < 64; ++j) { s[j] = __expf(s[j] - m); sum += s[j]; }
  float r = 1.f / sum;
  float o[16];
#pragma unroll
  for (int d = 0; d < 16; ++d) o[d] = 0.f;
#pragma unroll
  for (int j = 0; j < 64; ++j) {
    float vv[16];
    *(float4*)&vv[0]  = vls[wv][0][j];
    *(float4*)&vv[4]  = vls[wv][1][j];
    *(float4*)&vv[8]  = vls[wv][2][j];
    *(float4*)&vv[12] = vls[wv][3][j];
    float pj = s[j];
#pragma unroll
    for (int d = 0; d < 16; ++d) o[d] = fmaf(pj, vv[d], o[d]);
  }
#pragma unroll
  for (int d = 0; d < 16; ++d) o[d] *= r;
  float* op = out + base;
  *(float4*)(op)      = *(float4*)&o[0];
  *(float4*)(op + 4)  = *(float4*)&o[4];
  *(float4*)(op + 8)  = *(float4*)&o[8];
  *(float4*)(op + 12) = *(float4*)&o[12];
}

// ---------------- conv: 4-row strip blocks, 3-slot LDS ring, coalesced out --
// Staging layout per slot: chunk(ks,g',pp) at ks*8320 + g'*2080 + pp*16, g'=g^(pp&3).
// Transpose layout per slot (output): [pp][oc], row stride 208 B.
constexpr int kSlotB = 26624;        // >= max(24960 staging, 128*208 transpose)
constexpr int kChunks = 130 * 12;    // 1560 16-B chunks per staged row

__device__ __forceinline__ void stage_issue(const unsigned short* __restrict__ row,
                                            int x0, int t, us8 (&v)[7]) {
#pragma unroll
  for (int i = 0; i < 7; ++i) {
    int idx = i * 256 + t;
    if (idx < kChunks) {
      int pp = idx / 12, cb = idx % 12;
      int xx = x0 - 1 + pp;
      xx = xx < 0 ? 1 : (xx > 255 ? 254 : xx);
      v[i] = *(const us8*)(row + (size_t)xx * 96 + cb * 8);
    }
  }
}
__device__ __forceinline__ void stage_write(char* __restrict__ lds, int t, const us8 (&v)[7]) {
#pragma unroll
  for (int i = 0; i < 7; ++i) {
    int idx = i * 256 + t;
    if (idx < kChunks) {
      int pp = idx / 12, cb = idx % 12;
      int gq = cb & 3, ks = cb >> 2;
      int dst = ks * 8320 + ((gq ^ (pp & 3)) * 2080) + pp * 16;
      *(us8*)(lds + dst) = v[i];
    }
  }
}

__device__ __forceinline__ void conv_dy(
    const char* __restrict__ lds, const unsigned short* __restrict__ Wh,
    int tap0, int och, int xq, int col, int g, f32x4 (&acc)[3][4]) {
#pragma unroll
  for (int dx = 0; dx < 3; ++dx) {
    const char* ah = (const char*)Wh + ((size_t)(tap0 + dx) * 9216 + och * 4608 + col * 96 + g * 8) * 2;
    int ppb = xq * 64 + col + dx;
    const char* bp = lds + ((g ^ (ppb & 3)) * 2080 + ppb * 16);
#pragma unroll
    for (int ks = 0; ks < 3; ++ks) {
      short8 Ah[3], Bf[4];
#pragma unroll
      for (int mf = 0; mf < 3; ++mf)
        Ah[mf] = *(const short8*)(ah + (size_t)(mf * 16 * 96 + ks * 32) * 2);
#pragma unroll
      for (int nf = 0; nf < 4; ++nf)
        Bf[nf] = *(const short8*)(bp + ks * 8320 + nf * 256);
#pragma unroll
      for (int mf = 0; mf < 3; ++mf)
#pragma unroll
        for (int nf = 0; nf < 4; ++nf)
          acc[mf][nf] = __builtin_amdgcn_mfma_f32_16x16x32_bf16(Ah[mf], Bf[nf], acc[mf][nf], 0, 0, 0);
    }
  }
}

template <int MODE>
__global__ __launch_bounds__(256, 2) void conv_strip(
    const unsigned short* __restrict__ Wh,
    const unsigned short* __restrict__ B_, const float* __restrict__ bias,
    const float* __restrict__ attn, unsigned short* __restrict__ O_) {
  __shared__ char lds[3][kSlotB];
  int t = threadIdx.x, wv = t >> 6, lane = t & 63;
  int col = lane & 15, g = lane >> 4;
  int och = wv >> 1, xq = wv & 1;
  int bid = blockIdx.x;                    // 512 blocks
  int g8 = (bid & 7) * 64 + (bid >> 3);    // XCD-chunked
  int xh = g8 & 1;
  int grp = g8 >> 1;                       // 0..255
  int b = grp >> 6;
  int y0 = (grp & 63) * 4;
  int x0 = xh * 128;
  const unsigned short* Bb = B_ + (size_t)b * kHW * 96;

  us8 stg[7];
  // prologue: stage rows y0-1, y0, y0+1 into slots 0,1,2
#pragma unroll
  for (int k = 0; k < 3; ++k) {
    int r = y0 - 1 + k;
    int rr = r < 0 ? 1 : (r > 255 ? 254 : r);
    stage_issue(Bb + (size_t)rr * 256 * 96, x0, t, stg);
    stage_write(lds[k], t, stg);
  }
  __syncthreads();

#pragma unroll 1
  for (int i = 0; i < 4; ++i) {
    int y = y0 + i;
    bool pf = (i < 3);
    if (pf) {
      int r = y0 + i + 2;
      int rr = r > 255 ? 254 : r;
      stage_issue(Bb + (size_t)rr * 256 * 96, x0, t, stg);
    }
    f32x4 acc[3][4];
#pragma unroll
    for (int m = 0; m < 3; ++m)
#pragma unroll
      for (int n = 0; n < 4; ++n) acc[m][n] = (f32x4)0.f;

    conv_dy(lds[i % 3],       Wh, 0, och, xq, col, g, acc);
    conv_dy(lds[(i + 1) % 3], Wh, 3, och, xq, col, g, acc);
    conv_dy(lds[(i + 2) % 3], Wh, 6, och, xq, col, g, acc);
    __syncthreads();                        // all waves done reading slot i%3

    char* tb = lds[i % 3];                  // freed slot -> transpose buffer
    size_t prow = (size_t)b * kHW + (size_t)y * 256;
#pragma unroll
    for (int mf = 0; mf < 3; ++mf) {
      int oc0 = och * 48 + mf * 16 + g * 4;
      f32x4 bv;
#pragma unroll
      for (int r = 0; r < 4; ++r) bv[r] = bias[oc0 + r];
#pragma unroll
      for (int nf = 0; nf < 4; ++nf) {
        int pp = xq * 64 + nf * 16 + col;
        f32x4 v = acc[mf][nf] + bv;
        if (MODE == 0) {
#pragma unroll
          for (int r = 0; r < 4; ++r) v[r] = fmaxf(v[r], 0.f);
        } else {
          size_t p = prow + x0 + pp;
          float4 a = *(const float4*)(attn + ((size_t)(och * 3 + mf) * kP + p) * 16 + g * 4);
          v[0] += a.x; v[1] += a.y; v[2] += a.z; v[3] += a.w;
        }
        us4 o;
#pragma unroll
        for (int r = 0; r < 4; ++r) o[r] = f2bf(v[r]);
        *(us4*)(tb + pp * 208 + oc0 * 2) = o;
      }
    }
    __syncthreads();
    // coalesced store: thread t writes 96 contiguous bytes of the output row
    {
      int pp = t >> 1, half = t & 1;
      const char* src = tb + pp * 208 + half * 96;
      us8 o0 = *(const us8*)(src);
      us8 o1 = *(const us8*)(src + 16);
      us8 o2 = *(const us8*)(src + 32);
      us8 o3 = *(const us8*)(src + 48);
      us8 o4 = *(const us8*)(src + 64);
      us8 o5 = *(const us8*)(src + 80);
      unsigned short* dst = O_ + (prow + x0) * 96 + (size_t)t * 48;
      *(us8*)(dst)      = o0;
      *(us8*)(dst + 8)  = o1;
      *(us8*)(dst + 16) = o2;
      *(us8*)(dst + 24) = o3;
      *(us8*)(dst + 32) = o4;
      *(us8*)(dst + 40) = o5;
    }
    if (pf) {
      __syncthreads();                      // transpose reads done before overwrite
      stage_write(lds[i % 3], t, stg);
      __syncthreads();                      // staged row visible for next iter
    }
  }
}

// ---------------- final projection -> d_out NCHW fp32 ------------------------
__global__ __launch_bounds__(256, 2) void proj_gemm(
    const unsigned short* __restrict__ Wph, const unsigned short* __restrict__ Wpl,
    const unsigned short* __restrict__ S_, const float* __restrict__ bias,
    float* __restrict__ out) {
  int t = threadIdx.x, wv = t >> 6, lane = t & 63;
  size_t px0 = (size_t)blockIdx.x * 256 + wv * 64;
  int col = lane & 15, g = lane >> 4;
  f32x4 acc[6][4];
#pragma unroll
  for (int m = 0; m < 6; ++m)
#pragma unroll
    for (int n = 0; n < 4; ++n) acc[m][n] = (f32x4)0.f;
  const char* aH = (const char*)Wph + (size_t)(col * 96 + g * 8) * 2;
  const char* aL = (const char*)Wpl + (size_t)(col * 96 + g * 8) * 2;
  const char* bH = (const char*)S_ + ((px0 + col) * 96 + g * 8) * 2;
#pragma unroll
  for (int ks = 0; ks < 3; ++ks) {
    short8 Ah[6], Al[6], Bf[4];
#pragma unroll
    for (int mf = 0; mf < 6; ++mf) {
      Ah[mf] = *(const short8*)(aH + (size_t)(mf * 16 * 96 + ks * 32) * 2);
      Al[mf] = *(const short8*)(aL + (size_t)(mf * 16 * 96 + ks * 32) * 2);
    }
#pragma unroll
    for (int nf = 0; nf < 4; ++nf)
      Bf[nf] = *(const short8*)(bH + (size_t)(nf * 16 * 96 + ks * 32) * 2);
#pragma unroll
    for (int mf = 0; mf < 6; ++mf)
#pragma unroll
      for (int nf = 0; nf < 4; ++nf) {
        acc[mf][nf] = __builtin_amdgcn_mfma_f32_16x16x32_bf16(Ah[mf], Bf[nf], acc[mf][nf], 0, 0, 0);
        acc[mf][nf] = __builtin_amdgcn_mfma_f32_16x16x32_bf16(Al[mf], Bf[nf], acc[mf][nf], 0, 0, 0);
      }
  }
#pragma unroll
  for (int mf = 0; mf < 6; ++mf) {
    int oc0 = mf * 16 + g * 4;
#pragma unroll
    for (int nf = 0; nf < 4; ++nf) {
      size_t p = px0 + nf * 16 + col;
      size_t bb = p >> 16, pix = p & 65535;
      f32x4 v = acc[mf][nf];
#pragma unroll
      for (int r = 0; r < 4; ++r)
        out[(bb * 96 + oc0 + r) * (size_t)kHW + pix] = v[r] + bias[oc0 + r];
    }
  }
}

extern "C" void kernel_launch(void* const* d_in, const int* in_sizes, int n_in,
                              void* d_out, int out_size, void* d_ws, size_t ws_size,
                              hipStream_t stream) {
  const float* X       = (const float*)d_in[0];
  const float* V_w     = (const float*)d_in[1];
  const float* V_b     = (const float*)d_in[2];
  const float* QK_w    = (const float*)d_in[3];
  const float* QK_b    = (const float*)d_in[4];
  const float* meta_w1 = (const float*)d_in[5];
  const float* meta_b1 = (const float*)d_in[6];
  const float* meta_w2 = (const float*)d_in[7];
  const float* meta_b2 = (const float*)d_in[8];
  const float* conv1_w = (const float*)d_in[9];
  const float* conv1_b = (const float*)d_in[10];
  const float* conv2_w = (const float*)d_in[11];
  const float* conv2_b = (const float*)d_in[12];
  const float* proj_w  = (const float*)d_in[13];
  const float* proj_b  = (const float*)d_in[14];
  float* out = (float*)d_out;

  char* w = (char*)d_ws;
  const size_t PLANE = (size_t)kP * 96 * 2;      // 50,331,648 B
  unsigned short* Xh = (unsigned short*)(w + 0 * PLANE);
  unsigned short* Qp = (unsigned short*)(w + 1 * PLANE);
  unsigned short* Kp = (unsigned short*)(w + 2 * PLANE);
  unsigned short* Vr = (unsigned short*)(w + 3 * PLANE);
  float* bias_tab    = (float*)(w + 4 * PLANE);
  unsigned short* Wqh = (unsigned short*)(w + 4 * PLANE + 98304);
  unsigned short* Wql = Wqh + 27648;
  unsigned short* W1h = Wql + 27648;
  unsigned short* W2h = W1h + 82944;
  unsigned short* Wph = W2h + 82944;
  unsigned short* Wpl = Wph + 9216;
  // stream-ordered aliases
  unsigned short* T1r = Xh;            // X dead after qkv_gemm
  unsigned short* S2r = Qp;            // Q dead after attn
  float* attnF = out;                  // d_out as head-planar f32 scratch; proj overwrites

  bias_kernel<<<dim3(64), dim3(64), 0, stream>>>(meta_w1, meta_b1, meta_w2, meta_b2, bias_tab);
  prep_weights<<<dim3(324), dim3(256), 0, stream>>>(QK_w, V_w, conv1_w, conv2_w, proj_w,
                                                    Wqh, Wql, W1h, W2h, Wph, Wpl);
  split_x<<<dim3(4096), dim3(256), 0, stream>>>(X, Xh);
  qkv_gemm<<<dim3(1024), dim3(256), 0, stream>>>(Wqh, Wql, Xh, QK_b, V_b, Qp, Kp, Vr);
  attn_kernel<<<dim3(1024, 6), dim3(256), 0, stream>>>(Qp, Kp, Vr, bias_tab, attnF);
  conv_strip<0><<<dim3(512), dim3(256), 0, stream>>>(W1h, Vr, conv1_b, nullptr, T1r);
  conv_strip<1><<<dim3(512), dim3(256), 0, stream>>>(W2h, T1r, conv2_b, attnF, S2r);
  proj_gemm<<<dim3(1024), dim3(256), 0, stream>>>(Wph, Wpl, S2r, proj_b, out);
}

// Round 10
// 601.199 us; speedup vs baseline: 1.1269x; 1.1269x over previous
//
#include <hip/hip_runtime.h>
#include <cmath>

typedef short  short8 __attribute__((ext_vector_type(8)));
typedef float  f32x4  __attribute__((ext_vector_type(4)));
typedef unsigned short us8 __attribute__((ext_vector_type(8)));
typedef unsigned short us4 __attribute__((ext_vector_type(4)));

constexpr int kHW = 65536;           // 256*256
constexpr int kP  = 262144;          // 4 * kHW total pixels

__device__ __forceinline__ unsigned short f2bf(float x) {
  unsigned u = __builtin_bit_cast(unsigned, x);
  u += 0x7fffu + ((u >> 16) & 1u);
  return (unsigned short)(u >> 16);
}
__device__ __forceinline__ float bf2f(unsigned short h) {
  unsigned u = ((unsigned)h) << 16;
  return __builtin_bit_cast(float, u);
}
__device__ __forceinline__ void split2(float v, unsigned short& h, unsigned short& l) {
  unsigned short hh = f2bf(v);
  h = hh;
  l = f2bf(v - bf2f(hh));
}
__device__ __forceinline__ void gload16(const void* g, void* l) {
  __builtin_amdgcn_global_load_lds(
      (const __attribute__((address_space(1))) void*)g,
      (__attribute__((address_space(3))) void*)l, 16, 0, 0);
}

// ---------------- bias table: bias_tab[h][i][j], h<6, i,j<64 ----------------
__global__ void bias_kernel(const float* __restrict__ w1, const float* __restrict__ b1,
                            const float* __restrict__ w2, const float* __restrict__ b2,
                            float* __restrict__ bias_tab) {
  int i = blockIdx.x;
  int j = threadIdx.x;
  float dy = (float)((i >> 3) - (j >> 3));
  float dx = (float)((i & 7) - (j & 7));
  float r0 = copysignf(log1pf(fabsf(dy)), dy);
  float r1 = copysignf(log1pf(fabsf(dx)), dx);
  float acc[6];
#pragma unroll
  for (int h = 0; h < 6; ++h) acc[h] = b2[h];
  for (int t = 0; t < 256; ++t) {
    float hv = fmaf(r0, w1[t], fmaf(r1, w1[256 + t], b1[t]));
    hv = fmaxf(hv, 0.f);
#pragma unroll
    for (int h = 0; h < 6; ++h) acc[h] = fmaf(hv, w2[t * 6 + h], acc[h]);
  }
#pragma unroll
  for (int h = 0; h < 6; ++h) bias_tab[h * 4096 + i * 64 + j] = acc[h];
}

// ---------------- weight prep ------------------------------------------------
__global__ void prep_weights(const float* __restrict__ qk_w, const float* __restrict__ v_w,
                             const float* __restrict__ c1w, const float* __restrict__ c2w,
                             const float* __restrict__ pjw,
                             unsigned short* __restrict__ Wqh, unsigned short* __restrict__ Wql,
                             unsigned short* __restrict__ W1h,
                             unsigned short* __restrict__ W2h,
                             unsigned short* __restrict__ Wph, unsigned short* __restrict__ Wpl) {
  int i = blockIdx.x * 256 + threadIdx.x;
  if (i < 27648) {
    float v = (i < 18432) ? qk_w[i] : v_w[i - 18432];
    split2(v, Wqh[i], Wql[i]);
  }
  if (i < 82944) {
    int dlt = i / 9216;
    int oc  = (i / 96) % 96;
    int ic  = i % 96;
    int src = (oc * 96 + ic) * 9 + dlt;
    W1h[i] = f2bf(c1w[src]);
    W2h[i] = f2bf(c2w[src]);
  }
  if (i < 9216) split2(pjw[i], Wph[i], Wpl[i]);
}

// ---------------- X: NCHW fp32 -> NHWC bf16 (hi only) -----------------------
__global__ __launch_bounds__(256) void split_x(const float* __restrict__ X,
                                               unsigned short* __restrict__ Xh) {
  __shared__ float tile[96][65];
  int t = threadIdx.x;
  size_t p0 = (size_t)blockIdx.x * 64;
  int b = (int)(p0 >> 16), pix = (int)(p0 & 65535);
  const float* xb = X + (size_t)b * 96 * kHW + pix;
#pragma unroll
  for (int i = 0; i < 24; ++i) {
    int ic = (t >> 6) + i * 4;
    tile[ic][t & 63] = xb[(size_t)ic * kHW + (t & 63)];
  }
  __syncthreads();
  int px = t >> 2;
  size_t outbase = (p0 + px) * 96;
#pragma unroll
  for (int cc = 0; cc < 3; ++cc) {
    int c = (t & 3) + cc * 4;
    us8 h8;
#pragma unroll
    for (int j = 0; j < 8; ++j) h8[j] = f2bf(tile[c * 8 + j][px]);
    *(us8*)(Xh + outbase + c * 8) = h8;
  }
}

// ---------------- merged QKV GEMM: X read once, B-frags in regs -------------
__global__ __launch_bounds__(256, 2) void qkv_gemm(
    const unsigned short* __restrict__ Wqh, const unsigned short* __restrict__ Wql,
    const unsigned short* __restrict__ Xh,
    const float* __restrict__ qk_b, const float* __restrict__ v_b,
    unsigned short* __restrict__ Qp, unsigned short* __restrict__ Kp,
    unsigned short* __restrict__ Vr) {
  int t = threadIdx.x, wv = t >> 6, lane = t & 63;
  size_t px0 = (size_t)blockIdx.x * 256 + wv * 64;
  int col = lane & 15, g = lane >> 4;

  const char* bH = (const char*)Xh + ((px0 + col) * 96 + g * 8) * 2;
  short8 Bh[3][4];
#pragma unroll
  for (int ks = 0; ks < 3; ++ks)
#pragma unroll
    for (int nf = 0; nf < 4; ++nf)
      Bh[ks][nf] = *(const short8*)(bH + (size_t)(nf * 16 * 96 + ks * 32) * 2);

#pragma unroll 1
  for (int z = 0; z < 3; ++z) {
    f32x4 acc[6][4];
#pragma unroll
    for (int m = 0; m < 6; ++m)
#pragma unroll
      for (int n = 0; n < 4; ++n) acc[m][n] = (f32x4)0.f;
    const char* aH = (const char*)(Wqh + z * 9216) + (size_t)(col * 96 + g * 8) * 2;
    const char* aL = (const char*)(Wql + z * 9216) + (size_t)(col * 96 + g * 8) * 2;
#pragma unroll
    for (int ks = 0; ks < 3; ++ks) {
      short8 Ah[6], Al[6];
#pragma unroll
      for (int mf = 0; mf < 6; ++mf) {
        Ah[mf] = *(const short8*)(aH + (size_t)(mf * 16 * 96 + ks * 32) * 2);
        Al[mf] = *(const short8*)(aL + (size_t)(mf * 16 * 96 + ks * 32) * 2);
      }
#pragma unroll
      for (int mf = 0; mf < 6; ++mf)
#pragma unroll
        for (int nf = 0; nf < 4; ++nf) {
          acc[mf][nf] = __builtin_amdgcn_mfma_f32_16x16x32_bf16(Ah[mf], Bh[ks][nf], acc[mf][nf], 0, 0, 0);
          acc[mf][nf] = __builtin_amdgcn_mfma_f32_16x16x32_bf16(Al[mf], Bh[ks][nf], acc[mf][nf], 0, 0, 0);
        }
    }
    const float* bias = (z == 0) ? qk_b : (z == 1 ? qk_b + 96 : v_b);
    float scale = (z == 0) ? 0.25f : 1.f;
#pragma unroll
    for (int mf = 0; mf < 6; ++mf) {
      int oc0 = mf * 16 + g * 4;
      f32x4 bv;
#pragma unroll
      for (int r = 0; r < 4; ++r) bv[r] = bias[oc0 + r];
#pragma unroll
      for (int nf = 0; nf < 4; ++nf) {
        size_t p = px0 + nf * 16 + col;
        f32x4 v = (acc[mf][nf] + bv) * scale;
        us4 o;
#pragma unroll
        for (int r = 0; r < 4; ++r) o[r] = f2bf(v[r]);
        if (z == 0)      *(us4*)(Qp + ((size_t)mf * kP + p) * 16 + g * 4) = o;
        else if (z == 1) *(us4*)(Kp + ((size_t)mf * kP + p) * 16 + g * 4) = o;
        else             *(us4*)(Vr + p * 96 + oc0) = o;
      }
    }
  }
}

// ---------------- attention: Q/K head-planar, V from row buffer -------------
__global__ __launch_bounds__(256) void attn_kernel(
    const unsigned short* __restrict__ Qp, const unsigned short* __restrict__ Kp,
    const unsigned short* __restrict__ Vr, const float* __restrict__ bias_tab,
    float* __restrict__ out) {
  __shared__ float bs[64 * 65];
  __shared__ float4 kls[4][4][64];
  __shared__ float4 vls[4][4][64];
  int t = threadIdx.x;
  int wv = t >> 6, lane = t & 63;
  int h = blockIdx.y;
  int wid = blockIdx.x * 4 + wv;
  int b = wid >> 10, wy = (wid >> 5) & 31, wx = wid & 31;
  size_t p = ((size_t)b << 16) + (size_t)(wy * 8 + (lane >> 3)) * 256 + wx * 8 + (lane & 7);
  size_t base = ((size_t)h * kP + p) * 16;
  us8 q0 = *(const us8*)(Qp + base), q1 = *(const us8*)(Qp + base + 8);
  us8 k0 = *(const us8*)(Kp + base), k1 = *(const us8*)(Kp + base + 8);
  size_t vbase = p * 96 + h * 16;
  us8 v0 = *(const us8*)(Vr + vbase), v1 = *(const us8*)(Vr + vbase + 8);
  float q[16];
#pragma unroll
  for (int d = 0; d < 8; ++d) {
    q[d]     = bf2f(q0[d]);
    q[8 + d] = bf2f(q1[d]);
  }
  kls[wv][0][lane] = make_float4(bf2f(k0[0]), bf2f(k0[1]), bf2f(k0[2]), bf2f(k0[3]));
  kls[wv][1][lane] = make_float4(bf2f(k0[4]), bf2f(k0[5]), bf2f(k0[6]), bf2f(k0[7]));
  kls[wv][2][lane] = make_float4(bf2f(k1[0]), bf2f(k1[1]), bf2f(k1[2]), bf2f(k1[3]));
  kls[wv][3][lane] = make_float4(bf2f(k1[4]), bf2f(k1[5]), bf2f(k1[6]), bf2f(k1[7]));
  vls[wv][0][lane] = make_float4(bf2f(v0[0]), bf2f(v0[1]), bf2f(v0[2]), bf2f(v0[3]));
  vls[wv][1][lane] = make_float4(bf2f(v0[4]), bf2f(v0[5]), bf2f(v0[6]), bf2f(v0[7]));
  vls[wv][2][lane] = make_float4(bf2f(v1[0]), bf2f(v1[1]), bf2f(v1[2]), bf2f(v1[3]));
  vls[wv][3][lane] = make_float4(bf2f(v1[4]), bf2f(v1[5]), bf2f(v1[6]), bf2f(v1[7]));
  {
    const float* bp = bias_tab + h * 4096;
#pragma unroll
    for (int r0 = 0; r0 < 16; ++r0) {
      int r = wv * 16 + r0;
      bs[r * 65 + lane] = bp[r * 64 + lane];
    }
  }
  __syncthreads();

  const float* brow = bs + lane * 65;
  float s[64];
#pragma unroll
  for (int j = 0; j < 64; ++j) {
    float kk[16];
    *(float4*)&kk[0]  = kls[wv][0][j];
    *(float4*)&kk[4]  = kls[wv][1][j];
    *(float4*)&kk[8]  = kls[wv][2][j];
    *(float4*)&kk[12] = kls[wv][3][j];
    float dot = brow[j];
#pragma unroll
    for (int d = 0; d < 16; ++d) dot = fmaf(q[d], kk[d], dot);
    s[j] = dot;
  }
  float m = s[0];
#pragma unroll
  for (int j = 1; j < 64; ++j) m = fmaxf(m, s[j]);
  float sum = 0.f;
#pragma unroll
  for (int j = 0; j < 64; ++j) { s[j] = __expf(s[j] - m); sum += s[j]; }
  float r = 1.f / sum;
  float o[16];
#pragma unroll
  for (int d = 0; d < 16; ++d) o[d] = 0.f;
#pragma unroll
  for (int j = 0; j < 64; ++j) {
    float vv[16];
    *(float4*)&vv[0]  = vls[wv][0][j];
    *(float4*)&vv[4]  = vls[wv][1][j];
    *(float4*)&vv[8]  = vls[wv][2][j];
    *(float4*)&vv[12] = vls[wv][3][j];
    float pj = s[j];
#pragma unroll
    for (int d = 0; d < 16; ++d) o[d] = fmaf(pj, vv[d], o[d]);
  }
#pragma unroll
  for (int d = 0; d < 16; ++d) o[d] *= r;
  float* op = out + base;
  *(float4*)(op)      = *(float4*)&o[0];
  *(float4*)(op + 4)  = *(float4*)&o[4];
  *(float4*)(op + 8)  = *(float4*)&o[8];
  *(float4*)(op + 12) = *(float4*)&o[12];
}

// ---------------- conv: global_load_lds staging, 4 px-quarter waves ---------
// LDS slot layout: 16B chunk L = ks*520 + gp*130 + pp at byte L*16 (linear dst).
// Source pre-swizzle: chunk L holds row data (pixel pp, chan block ks*4 + g)
// with g = gp ^ (pp&3)  -> read at ks*8320 + (g^(pp&3))*2080 + pp*16.
constexpr int kChunks = 1560;        // 130 px * 12 chunks
constexpr int kSlotB  = kChunks * 16;

__device__ __forceinline__ void stage_rows(const unsigned short* __restrict__ row,
                                           char* slot, const int (&off)[7], int t) {
  int wvbase = t & 192;
#pragma unroll
  for (int i = 0; i < 7; ++i) {
    if (i < 6 || t < 24)
      gload16((const char*)row + off[i], slot + (i * 256 + wvbase) * 16);
  }
}

__device__ __forceinline__ void conv_dy(
    const char* __restrict__ lds, const unsigned short* __restrict__ Wh,
    int tap0, int xq, int col, int g, f32x4 (&acc)[6][2]) {
#pragma unroll
  for (int dx = 0; dx < 3; ++dx) {
    const char* ah = (const char*)Wh + ((size_t)(tap0 + dx) * 9216 + col * 96 + g * 8) * 2;
    int ppb = xq * 32 + col + dx;
#pragma unroll
    for (int ks = 0; ks < 3; ++ks) {
      short8 Ah[6], Bf[2];
#pragma unroll
      for (int mf = 0; mf < 6; ++mf)
        Ah[mf] = *(const short8*)(ah + (size_t)(mf * 16 * 96 + ks * 32) * 2);
#pragma unroll
      for (int nf = 0; nf < 2; ++nf) {
        int pp = ppb + nf * 16;
        Bf[nf] = *(const short8*)(lds + ks * 8320 + ((g ^ (pp & 3)) * 2080) + pp * 16);
      }
#pragma unroll
      for (int mf = 0; mf < 6; ++mf)
#pragma unroll
        for (int nf = 0; nf < 2; ++nf)
          acc[mf][nf] = __builtin_amdgcn_mfma_f32_16x16x32_bf16(Ah[mf], Bf[nf], acc[mf][nf], 0, 0, 0);
    }
  }
}

template <int MODE>
__global__ __launch_bounds__(256, 3) void conv_gl(
    const unsigned short* __restrict__ Wh,
    const unsigned short* __restrict__ B_, const float* __restrict__ bias,
    const float* __restrict__ attn, unsigned short* __restrict__ O_) {
  __shared__ char lds[2][kSlotB];
  int t = threadIdx.x, lane = t & 63;
  int col = lane & 15, g = lane >> 4;
  int xq = t >> 6;
  int bid = blockIdx.x;
  int g8 = (bid & 7) * 256 + (bid >> 3);   // XCD-chunked
  int xh = g8 & 1;
  int ry = g8 >> 1;
  int b = ry >> 8, y = ry & 255;
  int x0 = xh * 128;

  // per-thread pre-swizzled source offsets (bytes) for the 7 stage issues
  int off[7];
#pragma unroll
  for (int i = 0; i < 7; ++i) {
    int idx = i * 256 + t;
    int ks = idx / 520;
    int rem = idx - ks * 520;
    int gp = rem / 130;
    int pp = rem - gp * 130;
    int gg = gp ^ (pp & 3);
    int xx = x0 - 1 + pp;
    xx = xx < 0 ? 1 : (xx > 255 ? 254 : xx);
    off[i] = (xx * 96 + (ks * 4 + gg) * 8) * 2;
  }

  const unsigned short* Bb = B_ + (size_t)b * kHW * 96;
  int ym = (y == 0) ? 1 : y - 1;
  int yp = (y == 255) ? 254 : y + 1;

  f32x4 acc[6][2];
#pragma unroll
  for (int m = 0; m < 6; ++m)
#pragma unroll
    for (int n = 0; n < 2; ++n) acc[m][n] = (f32x4)0.f;

  stage_rows(Bb + (size_t)ym * 24576, lds[0], off, t);
  __syncthreads();                               // drain row y-1
  stage_rows(Bb + (size_t)y * 24576, lds[1], off, t);
  conv_dy(lds[0], Wh, 0, xq, col, g, acc);       // dy=0 while row y loads
  __syncthreads();                               // drain row y, done reading buf0
  stage_rows(Bb + (size_t)yp * 24576, lds[0], off, t);
  conv_dy(lds[1], Wh, 3, xq, col, g, acc);       // dy=1 while row y+1 loads
  __syncthreads();                               // drain row y+1
  conv_dy(lds[0], Wh, 6, xq, col, g, acc);       // dy=2

  size_t prow = (size_t)b * kHW + (size_t)y * 256;
#pragma unroll
  for (int mf = 0; mf < 6; ++mf) {
    int oc0 = mf * 16 + g * 4;
    f32x4 bv;
#pragma unroll
    for (int r = 0; r < 4; ++r) bv[r] = bias[oc0 + r];
#pragma unroll
    for (int nf = 0; nf < 2; ++nf) {
      int pp = xq * 32 + nf * 16 + col;
      size_t p = prow + x0 + pp;
      f32x4 v = acc[mf][nf] + bv;
      if (MODE == 0) {
#pragma unroll
        for (int r = 0; r < 4; ++r) v[r] = fmaxf(v[r], 0.f);
      } else {
        float4 a = *(const float4*)(attn + ((size_t)mf * kP + p) * 16 + g * 4);
        v[0] += a.x; v[1] += a.y; v[2] += a.z; v[3] += a.w;
      }
      us4 o;
#pragma unroll
      for (int r = 0; r < 4; ++r) o[r] = f2bf(v[r]);
      *(us4*)(O_ + p * 96 + oc0) = o;
    }
  }
}

// ---------------- final projection -> d_out NCHW fp32 ------------------------
__global__ __launch_bounds__(256, 2) void proj_gemm(
    const unsigned short* __restrict__ Wph, const unsigned short* __restrict__ Wpl,
    const unsigned short* __restrict__ S_, const float* __restrict__ bias,
    float* __restrict__ out) {
  int t = threadIdx.x, wv = t >> 6, lane = t & 63;
  size_t px0 = (size_t)blockIdx.x * 256 + wv * 64;
  int col = lane & 15, g = lane >> 4;
  f32x4 acc[6][4];
#pragma unroll
  for (int m = 0; m < 6; ++m)
#pragma unroll
    for (int n = 0; n < 4; ++n) acc[m][n] = (f32x4)0.f;
  const char* aH = (const char*)Wph + (size_t)(col * 96 + g * 8) * 2;
  const char* aL = (const char*)Wpl + (size_t)(col * 96 + g * 8) * 2;
  const char* bH = (const char*)S_ + ((px0 + col) * 96 + g * 8) * 2;
#pragma unroll
  for (int ks = 0; ks < 3; ++ks) {
    short8 Ah[6], Al[6], Bf[4];
#pragma unroll
    for (int mf = 0; mf < 6; ++mf) {
      Ah[mf] = *(const short8*)(aH + (size_t)(mf * 16 * 96 + ks * 32) * 2);
      Al[mf] = *(const short8*)(aL + (size_t)(mf * 16 * 96 + ks * 32) * 2);
    }
#pragma unroll
    for (int nf = 0; nf < 4; ++nf)
      Bf[nf] = *(const short8*)(bH + (size_t)(nf * 16 * 96 + ks * 32) * 2);
#pragma unroll
    for (int mf = 0; mf < 6; ++mf)
#pragma unroll
      for (int nf = 0; nf < 4; ++nf) {
        acc[mf][nf] = __builtin_amdgcn_mfma_f32_16x16x32_bf16(Ah[mf], Bf[nf], acc[mf][nf], 0, 0, 0);
        acc[mf][nf] = __builtin_amdgcn_mfma_f32_16x16x32_bf16(Al[mf], Bf[nf], acc[mf][nf], 0, 0, 0);
      }
  }
#pragma unroll
  for (int mf = 0; mf < 6; ++mf) {
    int oc0 = mf * 16 + g * 4;
#pragma unroll
    for (int nf = 0; nf < 4; ++nf) {
      size_t p = px0 + nf * 16 + col;
      size_t bb = p >> 16, pix = p & 65535;
      f32x4 v = acc[mf][nf];
#pragma unroll
      for (int r = 0; r < 4; ++r)
        out[(bb * 96 + oc0 + r) * (size_t)kHW + pix] = v[r] + bias[oc0 + r];
    }
  }
}

extern "C" void kernel_launch(void* const* d_in, const int* in_sizes, int n_in,
                              void* d_out, int out_size, void* d_ws, size_t ws_size,
                              hipStream_t stream) {
  const float* X       = (const float*)d_in[0];
  const float* V_w     = (const float*)d_in[1];
  const float* V_b     = (const float*)d_in[2];
  const float* QK_w    = (const float*)d_in[3];
  const float* QK_b    = (const float*)d_in[4];
  const float* meta_w1 = (const float*)d_in[5];
  const float* meta_b1 = (const float*)d_in[6];
  const float* meta_w2 = (const float*)d_in[7];
  const float* meta_b2 = (const float*)d_in[8];
  const float* conv1_w = (const float*)d_in[9];
  const float* conv1_b = (const float*)d_in[10];
  const float* conv2_w = (const float*)d_in[11];
  const float* conv2_b = (const float*)d_in[12];
  const float* proj_w  = (const float*)d_in[13];
  const float* proj_b  = (const float*)d_in[14];
  float* out = (float*)d_out;

  char* w = (char*)d_ws;
  const size_t PLANE = (size_t)kP * 96 * 2;      // 50,331,648 B
  unsigned short* Xh = (unsigned short*)(w + 0 * PLANE);
  unsigned short* Qp = (unsigned short*)(w + 1 * PLANE);
  unsigned short* Kp = (unsigned short*)(w + 2 * PLANE);
  unsigned short* Vr = (unsigned short*)(w + 3 * PLANE);
  float* bias_tab    = (float*)(w + 4 * PLANE);
  unsigned short* Wqh = (unsigned short*)(w + 4 * PLANE + 98304);
  unsigned short* Wql = Wqh + 27648;
  unsigned short* W1h = Wql + 27648;
  unsigned short* W2h = W1h + 82944;
  unsigned short* Wph = W2h + 82944;
  unsigned short* Wpl = Wph + 9216;
  // stream-ordered aliases
  unsigned short* T1r = Xh;            // X dead after qkv_gemm
  unsigned short* S2r = Qp;            // Q dead after attn
  float* attnF = out;                  // d_out as head-planar f32 scratch; proj overwrites

  bias_kernel<<<dim3(64), dim3(64), 0, stream>>>(meta_w1, meta_b1, meta_w2, meta_b2, bias_tab);
  prep_weights<<<dim3(324), dim3(256), 0, stream>>>(QK_w, V_w, conv1_w, conv2_w, proj_w,
                                                    Wqh, Wql, W1h, W2h, Wph, Wpl);
  split_x<<<dim3(4096), dim3(256), 0, stream>>>(X, Xh);
  qkv_gemm<<<dim3(1024), dim3(256), 0, stream>>>(Wqh, Wql, Xh, QK_b, V_b, Qp, Kp, Vr);
  attn_kernel<<<dim3(1024, 6), dim3(256), 0, stream>>>(Qp, Kp, Vr, bias_tab, attnF);
  conv_gl<0><<<dim3(2048), dim3(256), 0, stream>>>(W1h, Vr, conv1_b, nullptr, T1r);
  conv_gl<1><<<dim3(2048), dim3(256), 0, stream>>>(W2h, T1r, conv2_b, attnF, S2r);
  proj_gemm<<<dim3(1024), dim3(256), 0, stream>>>(Wph, Wpl, S2r, proj_b, out);
}

// Round 11
// 473.713 us; speedup vs baseline: 1.4301x; 1.2691x over previous
//
#include <hip/hip_runtime.h>
#include <cmath>

typedef short  short8 __attribute__((ext_vector_type(8)));
typedef float  f32x4  __attribute__((ext_vector_type(4)));
typedef unsigned short us8 __attribute__((ext_vector_type(8)));
typedef unsigned short us4 __attribute__((ext_vector_type(4)));

constexpr int kHW = 65536;           // 256*256
constexpr int kP  = 262144;          // 4 * kHW total pixels

__device__ __forceinline__ unsigned short f2bf(float x) {
  unsigned u = __builtin_bit_cast(unsigned, x);
  u += 0x7fffu + ((u >> 16) & 1u);
  return (unsigned short)(u >> 16);
}
__device__ __forceinline__ float bf2f(unsigned short h) {
  unsigned u = ((unsigned)h) << 16;
  return __builtin_bit_cast(float, u);
}
__device__ __forceinline__ void split2(float v, unsigned short& h, unsigned short& l) {
  unsigned short hh = f2bf(v);
  h = hh;
  l = f2bf(v - bf2f(hh));
}
__device__ __forceinline__ void gload16(const void* g, void* l) {
  __builtin_amdgcn_global_load_lds(
      (const __attribute__((address_space(1))) void*)g,
      (__attribute__((address_space(3))) void*)l, 16, 0, 0);
}

// ---------------- bias table: bias_tab[h][i][j], h<6, i,j<64 ----------------
__global__ void bias_kernel(const float* __restrict__ w1, const float* __restrict__ b1,
                            const float* __restrict__ w2, const float* __restrict__ b2,
                            float* __restrict__ bias_tab) {
  int i = blockIdx.x;
  int j = threadIdx.x;
  float dy = (float)((i >> 3) - (j >> 3));
  float dx = (float)((i & 7) - (j & 7));
  float r0 = copysignf(log1pf(fabsf(dy)), dy);
  float r1 = copysignf(log1pf(fabsf(dx)), dx);
  float acc[6];
#pragma unroll
  for (int h = 0; h < 6; ++h) acc[h] = b2[h];
  for (int t = 0; t < 256; ++t) {
    float hv = fmaf(r0, w1[t], fmaf(r1, w1[256 + t], b1[t]));
    hv = fmaxf(hv, 0.f);
#pragma unroll
    for (int h = 0; h < 6; ++h) acc[h] = fmaf(hv, w2[t * 6 + h], acc[h]);
  }
#pragma unroll
  for (int h = 0; h < 6; ++h) bias_tab[h * 4096 + i * 64 + j] = acc[h];
}

// ---------------- weight prep ------------------------------------------------
__global__ void prep_weights(const float* __restrict__ qk_w, const float* __restrict__ v_w,
                             const float* __restrict__ c1w, const float* __restrict__ c2w,
                             const float* __restrict__ pjw,
                             unsigned short* __restrict__ Wqh, unsigned short* __restrict__ Wql,
                             unsigned short* __restrict__ W1h,
                             unsigned short* __restrict__ W2h,
                             unsigned short* __restrict__ Wph, unsigned short* __restrict__ Wpl) {
  int i = blockIdx.x * 256 + threadIdx.x;
  if (i < 27648) {
    float v = (i < 18432) ? qk_w[i] : v_w[i - 18432];
    split2(v, Wqh[i], Wql[i]);
  }
  if (i < 82944) {
    int dlt = i / 9216;
    int oc  = (i / 96) % 96;
    int ic  = i % 96;
    int src = (oc * 96 + ic) * 9 + dlt;
    W1h[i] = f2bf(c1w[src]);
    W2h[i] = f2bf(c2w[src]);
  }
  if (i < 9216) split2(pjw[i], Wph[i], Wpl[i]);
}

// ---------------- X: NCHW fp32 -> NHWC bf16 (hi only) -----------------------
__global__ __launch_bounds__(256) void split_x(const float* __restrict__ X,
                                               unsigned short* __restrict__ Xh) {
  __shared__ float tile[96][65];
  int t = threadIdx.x;
  size_t p0 = (size_t)blockIdx.x * 64;
  int b = (int)(p0 >> 16), pix = (int)(p0 & 65535);
  const float* xb = X + (size_t)b * 96 * kHW + pix;
#pragma unroll
  for (int i = 0; i < 24; ++i) {
    int ic = (t >> 6) + i * 4;
    tile[ic][t & 63] = xb[(size_t)ic * kHW + (t & 63)];
  }
  __syncthreads();
  int px = t >> 2;
  size_t outbase = (p0 + px) * 96;
#pragma unroll
  for (int cc = 0; cc < 3; ++cc) {
    int c = (t & 3) + cc * 4;
    us8 h8;
#pragma unroll
    for (int j = 0; j < 8; ++j) h8[j] = f2bf(tile[c * 8 + j][px]);
    *(us8*)(Xh + outbase + c * 8) = h8;
  }
}

// ---------------- merged QKV GEMM: X read once, B-frags in regs -------------
__global__ __launch_bounds__(256, 2) void qkv_gemm(
    const unsigned short* __restrict__ Wqh, const unsigned short* __restrict__ Wql,
    const unsigned short* __restrict__ Xh,
    const float* __restrict__ qk_b, const float* __restrict__ v_b,
    unsigned short* __restrict__ Qp, unsigned short* __restrict__ Kp,
    unsigned short* __restrict__ Vr) {
  int t = threadIdx.x, wv = t >> 6, lane = t & 63;
  size_t px0 = (size_t)blockIdx.x * 256 + wv * 64;
  int col = lane & 15, g = lane >> 4;

  const char* bH = (const char*)Xh + ((px0 + col) * 96 + g * 8) * 2;
  short8 Bh[3][4];
#pragma unroll
  for (int ks = 0; ks < 3; ++ks)
#pragma unroll
    for (int nf = 0; nf < 4; ++nf)
      Bh[ks][nf] = *(const short8*)(bH + (size_t)(nf * 16 * 96 + ks * 32) * 2);

#pragma unroll 1
  for (int z = 0; z < 3; ++z) {
    f32x4 acc[6][4];
#pragma unroll
    for (int m = 0; m < 6; ++m)
#pragma unroll
      for (int n = 0; n < 4; ++n) acc[m][n] = (f32x4)0.f;
    const char* aH = (const char*)(Wqh + z * 9216) + (size_t)(col * 96 + g * 8) * 2;
    const char* aL = (const char*)(Wql + z * 9216) + (size_t)(col * 96 + g * 8) * 2;
#pragma unroll
    for (int ks = 0; ks < 3; ++ks) {
      short8 Ah[6], Al[6];
#pragma unroll
      for (int mf = 0; mf < 6; ++mf) {
        Ah[mf] = *(const short8*)(aH + (size_t)(mf * 16 * 96 + ks * 32) * 2);
        Al[mf] = *(const short8*)(aL + (size_t)(mf * 16 * 96 + ks * 32) * 2);
      }
#pragma unroll
      for (int mf = 0; mf < 6; ++mf)
#pragma unroll
        for (int nf = 0; nf < 4; ++nf) {
          acc[mf][nf] = __builtin_amdgcn_mfma_f32_16x16x32_bf16(Ah[mf], Bh[ks][nf], acc[mf][nf], 0, 0, 0);
          acc[mf][nf] = __builtin_amdgcn_mfma_f32_16x16x32_bf16(Al[mf], Bh[ks][nf], acc[mf][nf], 0, 0, 0);
        }
    }
    const float* bias = (z == 0) ? qk_b : (z == 1 ? qk_b + 96 : v_b);
    float scale = (z == 0) ? 0.25f : 1.f;
#pragma unroll
    for (int mf = 0; mf < 6; ++mf) {
      int oc0 = mf * 16 + g * 4;
      f32x4 bv;
#pragma unroll
      for (int r = 0; r < 4; ++r) bv[r] = bias[oc0 + r];
#pragma unroll
      for (int nf = 0; nf < 4; ++nf) {
        size_t p = px0 + nf * 16 + col;
        f32x4 v = (acc[mf][nf] + bv) * scale;
        us4 o;
#pragma unroll
        for (int r = 0; r < 4; ++r) o[r] = f2bf(v[r]);
        if (z == 0)      *(us4*)(Qp + ((size_t)mf * kP + p) * 16 + g * 4) = o;
        else if (z == 1) *(us4*)(Kp + ((size_t)mf * kP + p) * 16 + g * 4) = o;
        else             *(us4*)(Vr + p * 96 + oc0) = o;
      }
    }
  }
}

// ---------------- attention: bf16 head-planar out ---------------------------
__global__ __launch_bounds__(256) void attn_kernel(
    const unsigned short* __restrict__ Qp, const unsigned short* __restrict__ Kp,
    const unsigned short* __restrict__ Vr, const float* __restrict__ bias_tab,
    unsigned short* __restrict__ out) {
  __shared__ float bs[64 * 65];
  __shared__ float4 kls[4][4][64];
  __shared__ float4 vls[4][4][64];
  int t = threadIdx.x;
  int wv = t >> 6, lane = t & 63;
  int h = blockIdx.y;
  int wid = blockIdx.x * 4 + wv;
  int b = wid >> 10, wy = (wid >> 5) & 31, wx = wid & 31;
  size_t p = ((size_t)b << 16) + (size_t)(wy * 8 + (lane >> 3)) * 256 + wx * 8 + (lane & 7);
  size_t base = ((size_t)h * kP + p) * 16;
  us8 q0 = *(const us8*)(Qp + base), q1 = *(const us8*)(Qp + base + 8);
  us8 k0 = *(const us8*)(Kp + base), k1 = *(const us8*)(Kp + base + 8);
  size_t vbase = p * 96 + h * 16;
  us8 v0 = *(const us8*)(Vr + vbase), v1 = *(const us8*)(Vr + vbase + 8);
  float q[16];
#pragma unroll
  for (int d = 0; d < 8; ++d) {
    q[d]     = bf2f(q0[d]);
    q[8 + d] = bf2f(q1[d]);
  }
  kls[wv][0][lane] = make_float4(bf2f(k0[0]), bf2f(k0[1]), bf2f(k0[2]), bf2f(k0[3]));
  kls[wv][1][lane] = make_float4(bf2f(k0[4]), bf2f(k0[5]), bf2f(k0[6]), bf2f(k0[7]));
  kls[wv][2][lane] = make_float4(bf2f(k1[0]), bf2f(k1[1]), bf2f(k1[2]), bf2f(k1[3]));
  kls[wv][3][lane] = make_float4(bf2f(k1[4]), bf2f(k1[5]), bf2f(k1[6]), bf2f(k1[7]));
  vls[wv][0][lane] = make_float4(bf2f(v0[0]), bf2f(v0[1]), bf2f(v0[2]), bf2f(v0[3]));
  vls[wv][1][lane] = make_float4(bf2f(v0[4]), bf2f(v0[5]), bf2f(v0[6]), bf2f(v0[7]));
  vls[wv][2][lane] = make_float4(bf2f(v1[0]), bf2f(v1[1]), bf2f(v1[2]), bf2f(v1[3]));
  vls[wv][3][lane] = make_float4(bf2f(v1[4]), bf2f(v1[5]), bf2f(v1[6]), bf2f(v1[7]));
  {
    const float* bp = bias_tab + h * 4096;
#pragma unroll
    for (int r0 = 0; r0 < 16; ++r0) {
      int r = wv * 16 + r0;
      bs[r * 65 + lane] = bp[r * 64 + lane];
    }
  }
  __syncthreads();

  const float* brow = bs + lane * 65;
  float s[64];
#pragma unroll
  for (int j = 0; j < 64; ++j) {
    float kk[16];
    *(float4*)&kk[0]  = kls[wv][0][j];
    *(float4*)&kk[4]  = kls[wv][1][j];
    *(float4*)&kk[8]  = kls[wv][2][j];
    *(float4*)&kk[12] = kls[wv][3][j];
    float dot = brow[j];
#pragma unroll
    for (int d = 0; d < 16; ++d) dot = fmaf(q[d], kk[d], dot);
    s[j] = dot;
  }
  float m = s[0];
#pragma unroll
  for (int j = 1; j < 64; ++j) m = fmaxf(m, s[j]);
  float sum = 0.f;
#pragma unroll
  for (int j = 0; j < 64; ++j) { s[j] = __expf(s[j] - m); sum += s[j]; }
  float r = 1.f / sum;
  float o[16];
#pragma unroll
  for (int d = 0; d < 16; ++d) o[d] = 0.f;
#pragma unroll
  for (int j = 0; j < 64; ++j) {
    float vv[16];
    *(float4*)&vv[0]  = vls[wv][0][j];
    *(float4*)&vv[4]  = vls[wv][1][j];
    *(float4*)&vv[8]  = vls[wv][2][j];
    *(float4*)&vv[12] = vls[wv][3][j];
    float pj = s[j];
#pragma unroll
    for (int d = 0; d < 16; ++d) o[d] = fmaf(pj, vv[d], o[d]);
  }
  us8 o0, o1;
#pragma unroll
  for (int d = 0; d < 8; ++d) {
    o0[d] = f2bf(o[d] * r);
    o1[d] = f2bf(o[8 + d] * r);
  }
  unsigned short* op = out + base;
  *(us8*)(op)     = o0;
  *(us8*)(op + 8) = o1;
}

// ---------------- conv: gload_lds staging, och-split waves, coalesced out ---
// LDS slot: 16B chunk L = ks*520 + gp*130 + pp at byte L*16 (linear dst).
// Source pre-swizzle: chunk holds (pixel pp, chan block ks*4 + (gp^(pp&3)))
// -> read at ks*8320 + (g^(pp&3))*2080 + pp*16.
// Transpose epilogue layout: [pp][oc] stride 208 B in the free slot.
constexpr int kChunks = 1560;        // 130 px * 12 chunks
constexpr int kSlotB  = 26624;       // >= max(24960 staging, 128*208 transpose)

__device__ __forceinline__ void stage_rows(const unsigned short* __restrict__ row,
                                           char* slot, const int (&off)[7], int t) {
  int wvbase = t & 192;
#pragma unroll
  for (int i = 0; i < 7; ++i) {
    if (i < 6 || t < 24)
      gload16((const char*)row + off[i], slot + (i * 256 + wvbase) * 16);
  }
}

__device__ __forceinline__ void conv_dy(
    const char* __restrict__ lds, const unsigned short* __restrict__ Wh,
    int tap0, int och, int xq, int col, int g, f32x4 (&acc)[3][4]) {
#pragma unroll
  for (int dx = 0; dx < 3; ++dx) {
    const char* ah = (const char*)Wh + ((size_t)(tap0 + dx) * 9216 + och * 4608 + col * 96 + g * 8) * 2;
    int ppb = xq * 64 + col + dx;
#pragma unroll
    for (int ks = 0; ks < 3; ++ks) {
      short8 Ah[3], Bf[4];
#pragma unroll
      for (int mf = 0; mf < 3; ++mf)
        Ah[mf] = *(const short8*)(ah + (size_t)(mf * 16 * 96 + ks * 32) * 2);
#pragma unroll
      for (int nf = 0; nf < 4; ++nf) {
        int pp = ppb + nf * 16;
        Bf[nf] = *(const short8*)(lds + ks * 8320 + ((g ^ (pp & 3)) * 2080) + pp * 16);
      }
#pragma unroll
      for (int mf = 0; mf < 3; ++mf)
#pragma unroll
        for (int nf = 0; nf < 4; ++nf)
          acc[mf][nf] = __builtin_amdgcn_mfma_f32_16x16x32_bf16(Ah[mf], Bf[nf], acc[mf][nf], 0, 0, 0);
    }
  }
}

template <int MODE>
__global__ void conv_gl(
    const unsigned short* __restrict__ Wh,
    const unsigned short* __restrict__ B_, const float* __restrict__ bias,
    const unsigned short* __restrict__ attn, unsigned short* __restrict__ O_) {
  __shared__ char lds[2][kSlotB];
  int t = threadIdx.x, wv = t >> 6, lane = t & 63;
  int col = lane & 15, g = lane >> 4;
  int och = wv >> 1, xq = wv & 1;
  int bid = blockIdx.x;
  int g8 = (bid & 7) * 256 + (bid >> 3);   // XCD-chunked
  int xh = g8 & 1;
  int ry = g8 >> 1;
  int b = ry >> 8, y = ry & 255;
  int x0 = xh * 128;

  // per-thread pre-swizzled source offsets (bytes) for the 7 stage issues
  int off[7];
#pragma unroll
  for (int i = 0; i < 7; ++i) {
    int idx = i * 256 + t;
    int ks = idx / 520;
    int rem = idx - ks * 520;
    int gp = rem / 130;
    int pp = rem - gp * 130;
    int gg = gp ^ (pp & 3);
    int xx = x0 - 1 + pp;
    xx = xx < 0 ? 1 : (xx > 255 ? 254 : xx);
    off[i] = (xx * 96 + (ks * 4 + gg) * 8) * 2;
  }

  const unsigned short* Bb = B_ + (size_t)b * kHW * 96;
  int ym = (y == 0) ? 1 : y - 1;
  int yp = (y == 255) ? 254 : y + 1;

  f32x4 acc[3][4];
#pragma unroll
  for (int m = 0; m < 3; ++m)
#pragma unroll
    for (int n = 0; n < 4; ++n) acc[m][n] = (f32x4)0.f;

  stage_rows(Bb + (size_t)ym * 24576, lds[0], off, t);
  __syncthreads();                               // drain row y-1
  stage_rows(Bb + (size_t)y * 24576, lds[1], off, t);
  conv_dy(lds[0], Wh, 0, och, xq, col, g, acc);  // dy=0 while row y loads
  __syncthreads();                               // drain row y; buf0 free
  stage_rows(Bb + (size_t)yp * 24576, lds[0], off, t);
  conv_dy(lds[1], Wh, 3, och, xq, col, g, acc);  // dy=1 while row y+1 loads
  __syncthreads();                               // drain row y+1; buf1 free
  conv_dy(lds[0], Wh, 6, och, xq, col, g, acc);  // dy=2

  // epilogue: transpose through the free slot (lds[1]) -> coalesced stores
  char* tb = lds[1];
  size_t prow = (size_t)b * kHW + (size_t)y * 256;
#pragma unroll
  for (int mf = 0; mf < 3; ++mf) {
    int oc0 = och * 48 + mf * 16 + g * 4;
    f32x4 bv;
#pragma unroll
    for (int r = 0; r < 4; ++r) bv[r] = bias[oc0 + r];
#pragma unroll
    for (int nf = 0; nf < 4; ++nf) {
      int pp = xq * 64 + nf * 16 + col;
      f32x4 v = acc[mf][nf] + bv;
      if (MODE == 0) {
#pragma unroll
        for (int r = 0; r < 4; ++r) v[r] = fmaxf(v[r], 0.f);
      } else {
        size_t p = prow + x0 + pp;
        us4 a4 = *(const us4*)(attn + ((size_t)(och * 3 + mf) * kP + p) * 16 + g * 4);
#pragma unroll
        for (int r = 0; r < 4; ++r) v[r] += bf2f(a4[r]);
      }
      us4 o;
#pragma unroll
      for (int r = 0; r < 4; ++r) o[r] = f2bf(v[r]);
      *(us4*)(tb + pp * 208 + oc0 * 2) = o;
    }
  }
  __syncthreads();
  {
    int pp = t >> 1, half = t & 1;
    const char* src = tb + pp * 208 + half * 96;
    us8 o0 = *(const us8*)(src);
    us8 o1 = *(const us8*)(src + 16);
    us8 o2 = *(const us8*)(src + 32);
    us8 o3 = *(const us8*)(src + 48);
    us8 o4 = *(const us8*)(src + 64);
    us8 o5 = *(const us8*)(src + 80);
    unsigned short* dst = O_ + (prow + x0) * 96 + (size_t)t * 48;
    *(us8*)(dst)      = o0;
    *(us8*)(dst + 8)  = o1;
    *(us8*)(dst + 16) = o2;
    *(us8*)(dst + 24) = o3;
    *(us8*)(dst + 32) = o4;
    *(us8*)(dst + 40) = o5;
  }
}

// ---------------- final projection -> d_out NCHW fp32 ------------------------
__global__ __launch_bounds__(256, 2) void proj_gemm(
    const unsigned short* __restrict__ Wph, const unsigned short* __restrict__ Wpl,
    const unsigned short* __restrict__ S_, const float* __restrict__ bias,
    float* __restrict__ out) {
  int t = threadIdx.x, wv = t >> 6, lane = t & 63;
  size_t px0 = (size_t)blockIdx.x * 256 + wv * 64;
  int col = lane & 15, g = lane >> 4;
  f32x4 acc[6][4];
#pragma unroll
  for (int m = 0; m < 6; ++m)
#pragma unroll
    for (int n = 0; n < 4; ++n) acc[m][n] = (f32x4)0.f;
  const char* aH = (const char*)Wph + (size_t)(col * 96 + g * 8) * 2;
  const char* aL = (const char*)Wpl + (size_t)(col * 96 + g * 8) * 2;
  const char* bH = (const char*)S_ + ((px0 + col) * 96 + g * 8) * 2;
#pragma unroll
  for (int ks = 0; ks < 3; ++ks) {
    short8 Ah[6], Al[6], Bf[4];
#pragma unroll
    for (int mf = 0; mf < 6; ++mf) {
      Ah[mf] = *(const short8*)(aH + (size_t)(mf * 16 * 96 + ks * 32) * 2);
      Al[mf] = *(const short8*)(aL + (size_t)(mf * 16 * 96 + ks * 32) * 2);
    }
#pragma unroll
    for (int nf = 0; nf < 4; ++nf)
      Bf[nf] = *(const short8*)(bH + (size_t)(nf * 16 * 96 + ks * 32) * 2);
#pragma unroll
    for (int mf = 0; mf < 6; ++mf)
#pragma unroll
      for (int nf = 0; nf < 4; ++nf) {
        acc[mf][nf] = __builtin_amdgcn_mfma_f32_16x16x32_bf16(Ah[mf], Bf[nf], acc[mf][nf], 0, 0, 0);
        acc[mf][nf] = __builtin_amdgcn_mfma_f32_16x16x32_bf16(Al[mf], Bf[nf], acc[mf][nf], 0, 0, 0);
      }
  }
#pragma unroll
  for (int mf = 0; mf < 6; ++mf) {
    int oc0 = mf * 16 + g * 4;
#pragma unroll
    for (int nf = 0; nf < 4; ++nf) {
      size_t p = px0 + nf * 16 + col;
      size_t bb = p >> 16, pix = p & 65535;
      f32x4 v = acc[mf][nf];
#pragma unroll
      for (int r = 0; r < 4; ++r)
        out[(bb * 96 + oc0 + r) * (size_t)kHW + pix] = v[r] + bias[oc0 + r];
    }
  }
}

extern "C" void kernel_launch(void* const* d_in, const int* in_sizes, int n_in,
                              void* d_out, int out_size, void* d_ws, size_t ws_size,
                              hipStream_t stream) {
  const float* X       = (const float*)d_in[0];
  const float* V_w     = (const float*)d_in[1];
  const float* V_b     = (const float*)d_in[2];
  const float* QK_w    = (const float*)d_in[3];
  const float* QK_b    = (const float*)d_in[4];
  const float* meta_w1 = (const float*)d_in[5];
  const float* meta_b1 = (const float*)d_in[6];
  const float* meta_w2 = (const float*)d_in[7];
  const float* meta_b2 = (const float*)d_in[8];
  const float* conv1_w = (const float*)d_in[9];
  const float* conv1_b = (const float*)d_in[10];
  const float* conv2_w = (const float*)d_in[11];
  const float* conv2_b = (const float*)d_in[12];
  const float* proj_w  = (const float*)d_in[13];
  const float* proj_b  = (const float*)d_in[14];
  float* out = (float*)d_out;

  char* w = (char*)d_ws;
  const size_t PLANE = (size_t)kP * 96 * 2;      // 50,331,648 B
  unsigned short* Xh = (unsigned short*)(w + 0 * PLANE);
  unsigned short* Qp = (unsigned short*)(w + 1 * PLANE);
  unsigned short* Kp = (unsigned short*)(w + 2 * PLANE);
  unsigned short* Vr = (unsigned short*)(w + 3 * PLANE);
  float* bias_tab    = (float*)(w + 4 * PLANE);
  unsigned short* Wqh = (unsigned short*)(w + 4 * PLANE + 98304);
  unsigned short* Wql = Wqh + 27648;
  unsigned short* W1h = Wql + 27648;
  unsigned short* W2h = W1h + 82944;
  unsigned short* Wph = W2h + 82944;
  unsigned short* Wpl = Wph + 9216;
  // stream-ordered aliases
  unsigned short* T1r = Xh;            // X dead after qkv_gemm
  unsigned short* S2r = Qp;            // Q dead after attn
  unsigned short* attnB = (unsigned short*)out;  // d_out as bf16 head-planar scratch

  bias_kernel<<<dim3(64), dim3(64), 0, stream>>>(meta_w1, meta_b1, meta_w2, meta_b2, bias_tab);
  prep_weights<<<dim3(324), dim3(256), 0, stream>>>(QK_w, V_w, conv1_w, conv2_w, proj_w,
                                                    Wqh, Wql, W1h, W2h, Wph, Wpl);
  split_x<<<dim3(4096), dim3(256), 0, stream>>>(X, Xh);
  qkv_gemm<<<dim3(1024), dim3(256), 0, stream>>>(Wqh, Wql, Xh, QK_b, V_b, Qp, Kp, Vr);
  attn_kernel<<<dim3(1024, 6), dim3(256), 0, stream>>>(Qp, Kp, Vr, bias_tab, attnB);
  conv_gl<0><<<dim3(2048), dim3(256), 0, stream>>>(W1h, Vr, conv1_b, nullptr, T1r);
  conv_gl<1><<<dim3(2048), dim3(256), 0, stream>>>(W2h, T1r, conv2_b, attnB, S2r);
  proj_gemm<<<dim3(1024), dim3(256), 0, stream>>>(Wph, Wpl, S2r, proj_b, out);
}

// Round 12
// 432.654 us; speedup vs baseline: 1.5659x; 1.0949x over previous
//
#include <hip/hip_runtime.h>
#include <cmath>

typedef short  short8 __attribute__((ext_vector_type(8)));
typedef float  f32x4  __attribute__((ext_vector_type(4)));
typedef unsigned short us8 __attribute__((ext_vector_type(8)));
typedef unsigned short us4 __attribute__((ext_vector_type(4)));

constexpr int kHW = 65536;           // 256*256
constexpr int kP  = 262144;          // 4 * kHW total pixels

__device__ __forceinline__ unsigned short f2bf(float x) {
  unsigned u = __builtin_bit_cast(unsigned, x);
  u += 0x7fffu + ((u >> 16) & 1u);
  return (unsigned short)(u >> 16);
}
__device__ __forceinline__ float bf2f(unsigned short h) {
  unsigned u = ((unsigned)h) << 16;
  return __builtin_bit_cast(float, u);
}
__device__ __forceinline__ void split2(float v, unsigned short& h, unsigned short& l) {
  unsigned short hh = f2bf(v);
  h = hh;
  l = f2bf(v - bf2f(hh));
}
__device__ __forceinline__ void gload16(const void* g, void* l) {
  __builtin_amdgcn_global_load_lds(
      (const __attribute__((address_space(1))) void*)g,
      (__attribute__((address_space(3))) void*)l, 16, 0, 0);
}

// ---------------- bias table: bias_tab[h][i][j], h<6, i,j<64 ----------------
__global__ void bias_kernel(const float* __restrict__ w1, const float* __restrict__ b1,
                            const float* __restrict__ w2, const float* __restrict__ b2,
                            float* __restrict__ bias_tab) {
  int i = blockIdx.x;
  int j = threadIdx.x;
  float dy = (float)((i >> 3) - (j >> 3));
  float dx = (float)((i & 7) - (j & 7));
  float r0 = copysignf(log1pf(fabsf(dy)), dy);
  float r1 = copysignf(log1pf(fabsf(dx)), dx);
  float acc[6];
#pragma unroll
  for (int h = 0; h < 6; ++h) acc[h] = b2[h];
  for (int t = 0; t < 256; ++t) {
    float hv = fmaf(r0, w1[t], fmaf(r1, w1[256 + t], b1[t]));
    hv = fmaxf(hv, 0.f);
#pragma unroll
    for (int h = 0; h < 6; ++h) acc[h] = fmaf(hv, w2[t * 6 + h], acc[h]);
  }
#pragma unroll
  for (int h = 0; h < 6; ++h) bias_tab[h * 4096 + i * 64 + j] = acc[h];
}

// ---------------- weight prep ------------------------------------------------
__global__ void prep_weights(const float* __restrict__ qk_w, const float* __restrict__ v_w,
                             const float* __restrict__ c1w, const float* __restrict__ c2w,
                             const float* __restrict__ pjw,
                             unsigned short* __restrict__ Wqh, unsigned short* __restrict__ Wql,
                             unsigned short* __restrict__ W1h,
                             unsigned short* __restrict__ W2h,
                             unsigned short* __restrict__ Wph, unsigned short* __restrict__ Wpl) {
  int i = blockIdx.x * 256 + threadIdx.x;
  if (i < 27648) {
    float v = (i < 18432) ? qk_w[i] : v_w[i - 18432];
    split2(v, Wqh[i], Wql[i]);
  }
  if (i < 82944) {
    int dlt = i / 9216;
    int oc  = (i / 96) % 96;
    int ic  = i % 96;
    int src = (oc * 96 + ic) * 9 + dlt;
    W1h[i] = f2bf(c1w[src]);
    W2h[i] = f2bf(c2w[src]);
  }
  if (i < 9216) split2(pjw[i], Wph[i], Wpl[i]);
}

// ---------------- X: NCHW fp32 -> NHWC bf16 (hi only) -----------------------
__global__ __launch_bounds__(256) void split_x(const float* __restrict__ X,
                                               unsigned short* __restrict__ Xh) {
  __shared__ float tile[96][65];
  int t = threadIdx.x;
  size_t p0 = (size_t)blockIdx.x * 64;
  int b = (int)(p0 >> 16), pix = (int)(p0 & 65535);
  const float* xb = X + (size_t)b * 96 * kHW + pix;
#pragma unroll
  for (int i = 0; i < 24; ++i) {
    int ic = (t >> 6) + i * 4;
    tile[ic][t & 63] = xb[(size_t)ic * kHW + (t & 63)];
  }
  __syncthreads();
  int px = t >> 2;
  size_t outbase = (p0 + px) * 96;
#pragma unroll
  for (int cc = 0; cc < 3; ++cc) {
    int c = (t & 3) + cc * 4;
    us8 h8;
#pragma unroll
    for (int j = 0; j < 8; ++j) h8[j] = f2bf(tile[c * 8 + j][px]);
    *(us8*)(Xh + outbase + c * 8) = h8;
  }
}

// ---------------- merged QKV GEMM: X read once, B-frags in regs -------------
__global__ __launch_bounds__(256, 2) void qkv_gemm(
    const unsigned short* __restrict__ Wqh, const unsigned short* __restrict__ Wql,
    const unsigned short* __restrict__ Xh,
    const float* __restrict__ qk_b, const float* __restrict__ v_b,
    unsigned short* __restrict__ Qp, unsigned short* __restrict__ Kp,
    unsigned short* __restrict__ Vr) {
  int t = threadIdx.x, wv = t >> 6, lane = t & 63;
  size_t px0 = (size_t)blockIdx.x * 256 + wv * 64;
  int col = lane & 15, g = lane >> 4;

  const char* bH = (const char*)Xh + ((px0 + col) * 96 + g * 8) * 2;
  short8 Bh[3][4];
#pragma unroll
  for (int ks = 0; ks < 3; ++ks)
#pragma unroll
    for (int nf = 0; nf < 4; ++nf)
      Bh[ks][nf] = *(const short8*)(bH + (size_t)(nf * 16 * 96 + ks * 32) * 2);

#pragma unroll 1
  for (int z = 0; z < 3; ++z) {
    f32x4 acc[6][4];
#pragma unroll
    for (int m = 0; m < 6; ++m)
#pragma unroll
      for (int n = 0; n < 4; ++n) acc[m][n] = (f32x4)0.f;
    const char* aH = (const char*)(Wqh + z * 9216) + (size_t)(col * 96 + g * 8) * 2;
    const char* aL = (const char*)(Wql + z * 9216) + (size_t)(col * 96 + g * 8) * 2;
#pragma unroll
    for (int ks = 0; ks < 3; ++ks) {
      short8 Ah[6], Al[6];
#pragma unroll
      for (int mf = 0; mf < 6; ++mf) {
        Ah[mf] = *(const short8*)(aH + (size_t)(mf * 16 * 96 + ks * 32) * 2);
        Al[mf] = *(const short8*)(aL + (size_t)(mf * 16 * 96 + ks * 32) * 2);
      }
#pragma unroll
      for (int mf = 0; mf < 6; ++mf)
#pragma unroll
        for (int nf = 0; nf < 4; ++nf) {
          acc[mf][nf] = __builtin_amdgcn_mfma_f32_16x16x32_bf16(Ah[mf], Bh[ks][nf], acc[mf][nf], 0, 0, 0);
          acc[mf][nf] = __builtin_amdgcn_mfma_f32_16x16x32_bf16(Al[mf], Bh[ks][nf], acc[mf][nf], 0, 0, 0);
        }
    }
    const float* bias = (z == 0) ? qk_b : (z == 1 ? qk_b + 96 : v_b);
    float scale = (z == 0) ? 0.25f : 1.f;
#pragma unroll
    for (int mf = 0; mf < 6; ++mf) {
      int oc0 = mf * 16 + g * 4;
      f32x4 bv;
#pragma unroll
      for (int r = 0; r < 4; ++r) bv[r] = bias[oc0 + r];
#pragma unroll
      for (int nf = 0; nf < 4; ++nf) {
        size_t p = px0 + nf * 16 + col;
        f32x4 v = (acc[mf][nf] + bv) * scale;
        us4 o;
#pragma unroll
        for (int r = 0; r < 4; ++r) o[r] = f2bf(v[r]);
        if (z == 0)      *(us4*)(Qp + ((size_t)mf * kP + p) * 16 + g * 4) = o;
        else if (z == 1) *(us4*)(Kp + ((size_t)mf * kP + p) * 16 + g * 4) = o;
        else             *(us4*)(Vr + p * 96 + oc0) = o;
      }
    }
  }
}

// ---------------- attention via MFMA (wave = one window-head) ---------------
// QK^T swapped: D[k][q] = mfma(A=K rows, B=Q cols), d=16 zero-padded to K=32,
// bias preloaded as C-operand (f32 L2 reads, D-layout).
// Softmax lane-local (16 k per lane) + shfl_xor(16,32).
// PV: P -> LDS PT[q][k] bf16 (stride 72), V -> LDS VT[d][k]; O = mfma(P, V^T).
__global__ __launch_bounds__(256) void attn_mfma(
    const unsigned short* __restrict__ Qp, const unsigned short* __restrict__ Kp,
    const unsigned short* __restrict__ Vr, const float* __restrict__ bias_tab,
    unsigned short* __restrict__ out) {
  __shared__ unsigned short PT[4][64 * 72];   // per-wave P[q][k] bf16; reused as O[q][d]
  __shared__ unsigned short VT[4][16 * 72];   // per-wave V^T[d][k] bf16
  __shared__ float rls[4][64];                // per-wave 1/sum per q

  int t = threadIdx.x;
  int wv = t >> 6, lane = t & 63;
  int l15 = lane & 15, g = lane >> 4;
  int h = blockIdx.y;
  int wid = blockIdx.x * 4 + wv;
  int b = wid >> 10, wy = (wid >> 5) & 31, wx = wid & 31;
  size_t p0 = ((size_t)b << 16) + (size_t)wy * 8 * 256 + (size_t)wx * 8;
  const float* bt = bias_tab + h * 4096;

  // C-init: bias[q=col][k=row] in D layout (L2-resident reads)
  f32x4 acc[4][4];   // [kf][qf]
#pragma unroll
  for (int kf = 0; kf < 4; ++kf)
#pragma unroll
    for (int qf = 0; qf < 4; ++qf)
      acc[kf][qf] = *(const f32x4*)(bt + (qf * 16 + l15) * 64 + kf * 16 + g * 4);

  // A = K fragments (rows k, K-dim = d zero-padded), B = Q fragments (cols q)
  short8 Af[4], Bf[4];
#pragma unroll
  for (int f = 0; f < 4; ++f) {
    int kk = f * 16 + l15;
    size_t pk = p0 + (size_t)(kk >> 3) * 256 + (kk & 7);
    if (g < 2) {
      Af[f] = *(const short8*)(Kp + ((size_t)h * kP + pk) * 16 + g * 8);
      Bf[f] = *(const short8*)(Qp + ((size_t)h * kP + pk) * 16 + g * 8);
    } else {
      Af[f] = (short8)0;
      Bf[f] = (short8)0;
    }
  }

  // stage V^T[d][k] (own window pixel's 16 channels)
  {
    size_t pv = p0 + (size_t)(lane >> 3) * 256 + (lane & 7);
    const unsigned short* vp = Vr + pv * 96 + h * 16;
    us8 v0 = *(const us8*)(vp), v1 = *(const us8*)(vp + 8);
    unsigned short* vt = VT[wv];
#pragma unroll
    for (int d = 0; d < 8; ++d) {
      vt[d * 72 + lane]       = v0[d];
      vt[(d + 8) * 72 + lane] = v1[d];
    }
  }

  // QK^T
#pragma unroll
  for (int kf = 0; kf < 4; ++kf)
#pragma unroll
    for (int qf = 0; qf < 4; ++qf)
      acc[kf][qf] = __builtin_amdgcn_mfma_f32_16x16x32_bf16(Af[kf], Bf[qf], acc[kf][qf], 0, 0, 0);

  // softmax over k per q-column (lane holds q = qf*16+l15, 16 k values)
#pragma unroll
  for (int qf = 0; qf < 4; ++qf) {
    float m = acc[0][qf][0];
#pragma unroll
    for (int kf = 0; kf < 4; ++kf)
#pragma unroll
      for (int r = 0; r < 4; ++r) m = fmaxf(m, acc[kf][qf][r]);
    m = fmaxf(m, __shfl_xor(m, 16));
    m = fmaxf(m, __shfl_xor(m, 32));
    float sum = 0.f;
#pragma unroll
    for (int kf = 0; kf < 4; ++kf)
#pragma unroll
      for (int r = 0; r < 4; ++r) {
        float pe = __expf(acc[kf][qf][r] - m);
        acc[kf][qf][r] = pe;
        sum += pe;
      }
    sum += __shfl_xor(sum, 16);
    sum += __shfl_xor(sum, 32);
    if (g == 0) rls[wv][qf * 16 + l15] = 1.f / sum;
  }

  // store P (un-normalized) to PT[q][k] bf16
  unsigned short* pt = PT[wv];
#pragma unroll
  for (int qf = 0; qf < 4; ++qf)
#pragma unroll
    for (int kf = 0; kf < 4; ++kf) {
      us4 pb;
#pragma unroll
      for (int r = 0; r < 4; ++r) pb[r] = f2bf(acc[kf][qf][r]);
      *(us4*)&pt[(qf * 16 + l15) * 72 + kf * 16 + g * 4] = pb;
    }

  // PV: O[q][d] = sum_k P[q][k] * V^T[d][k]
  short8 Pa[4][2], Vb[2];
#pragma unroll
  for (int qf = 0; qf < 4; ++qf)
#pragma unroll
    for (int kc = 0; kc < 2; ++kc)
      Pa[qf][kc] = *(const short8*)&pt[(qf * 16 + l15) * 72 + kc * 32 + g * 8];
#pragma unroll
  for (int kc = 0; kc < 2; ++kc)
    Vb[kc] = *(const short8*)&VT[wv][l15 * 72 + kc * 32 + g * 8];
  f32x4 o[4];
#pragma unroll
  for (int qf = 0; qf < 4; ++qf) {
    o[qf] = (f32x4)0.f;
#pragma unroll
    for (int kc = 0; kc < 2; ++kc)
      o[qf] = __builtin_amdgcn_mfma_f32_16x16x32_bf16(Pa[qf][kc], Vb[kc], o[qf], 0, 0, 0);
  }

  // normalize and transpose through freed PT (O[q][d]), then coalesced out
#pragma unroll
  for (int qf = 0; qf < 4; ++qf) {
    f32x4 rv = *(const f32x4*)&rls[wv][qf * 16 + g * 4];
#pragma unroll
    for (int r = 0; r < 4; ++r)
      pt[(qf * 16 + g * 4 + r) * 72 + l15] = f2bf(o[qf][r] * rv[r]);
  }
  {
    int q = lane;
    us8 o0 = *(const us8*)&pt[q * 72];
    us8 o1 = *(const us8*)&pt[q * 72 + 8];
    size_t pq = p0 + (size_t)(q >> 3) * 256 + (q & 7);
    unsigned short* op = out + ((size_t)h * kP + pq) * 16;
    *(us8*)(op)     = o0;
    *(us8*)(op + 8) = o1;
  }
}

// ---------------- conv: gload_lds staging, och-split waves, coalesced out ---
constexpr int kChunks = 1560;        // 130 px * 12 chunks
constexpr int kSlotB  = 26624;       // >= max(24960 staging, 128*208 transpose)

__device__ __forceinline__ void stage_rows(const unsigned short* __restrict__ row,
                                           char* slot, const int (&off)[7], int t) {
  int wvbase = t & 192;
#pragma unroll
  for (int i = 0; i < 7; ++i) {
    if (i < 6 || t < 24)
      gload16((const char*)row + off[i], slot + (i * 256 + wvbase) * 16);
  }
}

__device__ __forceinline__ void conv_dy(
    const char* __restrict__ lds, const unsigned short* __restrict__ Wh,
    int tap0, int och, int xq, int col, int g, f32x4 (&acc)[3][4]) {
#pragma unroll
  for (int dx = 0; dx < 3; ++dx) {
    const char* ah = (const char*)Wh + ((size_t)(tap0 + dx) * 9216 + och * 4608 + col * 96 + g * 8) * 2;
    int ppb = xq * 64 + col + dx;
#pragma unroll
    for (int ks = 0; ks < 3; ++ks) {
      short8 Ah[3], Bf[4];
#pragma unroll
      for (int mf = 0; mf < 3; ++mf)
        Ah[mf] = *(const short8*)(ah + (size_t)(mf * 16 * 96 + ks * 32) * 2);
#pragma unroll
      for (int nf = 0; nf < 4; ++nf) {
        int pp = ppb + nf * 16;
        Bf[nf] = *(const short8*)(lds + ks * 8320 + ((g ^ (pp & 3)) * 2080) + pp * 16);
      }
#pragma unroll
      for (int mf = 0; mf < 3; ++mf)
#pragma unroll
        for (int nf = 0; nf < 4; ++nf)
          acc[mf][nf] = __builtin_amdgcn_mfma_f32_16x16x32_bf16(Ah[mf], Bf[nf], acc[mf][nf], 0, 0, 0);
    }
  }
}

template <int MODE>
__global__ void conv_gl(
    const unsigned short* __restrict__ Wh,
    const unsigned short* __restrict__ B_, const float* __restrict__ bias,
    const unsigned short* __restrict__ attn, unsigned short* __restrict__ O_) {
  __shared__ char lds[2][kSlotB];
  int t = threadIdx.x, wv = t >> 6, lane = t & 63;
  int col = lane & 15, g = lane >> 4;
  int och = wv >> 1, xq = wv & 1;
  int bid = blockIdx.x;
  int g8 = (bid & 7) * 256 + (bid >> 3);   // XCD-chunked
  int xh = g8 & 1;
  int ry = g8 >> 1;
  int b = ry >> 8, y = ry & 255;
  int x0 = xh * 128;

  int off[7];
#pragma unroll
  for (int i = 0; i < 7; ++i) {
    int idx = i * 256 + t;
    int ks = idx / 520;
    int rem = idx - ks * 520;
    int gp = rem / 130;
    int pp = rem - gp * 130;
    int gg = gp ^ (pp & 3);
    int xx = x0 - 1 + pp;
    xx = xx < 0 ? 1 : (xx > 255 ? 254 : xx);
    off[i] = (xx * 96 + (ks * 4 + gg) * 8) * 2;
  }

  const unsigned short* Bb = B_ + (size_t)b * kHW * 96;
  int ym = (y == 0) ? 1 : y - 1;
  int yp = (y == 255) ? 254 : y + 1;

  f32x4 acc[3][4];
#pragma unroll
  for (int m = 0; m < 3; ++m)
#pragma unroll
    for (int n = 0; n < 4; ++n) acc[m][n] = (f32x4)0.f;

  stage_rows(Bb + (size_t)ym * 24576, lds[0], off, t);
  __syncthreads();                               // drain row y-1
  stage_rows(Bb + (size_t)y * 24576, lds[1], off, t);
  conv_dy(lds[0], Wh, 0, och, xq, col, g, acc);  // dy=0 while row y loads
  __syncthreads();                               // drain row y; buf0 free
  stage_rows(Bb + (size_t)yp * 24576, lds[0], off, t);
  conv_dy(lds[1], Wh, 3, och, xq, col, g, acc);  // dy=1 while row y+1 loads
  __syncthreads();                               // drain row y+1; buf1 free
  conv_dy(lds[0], Wh, 6, och, xq, col, g, acc);  // dy=2

  // epilogue: transpose through the free slot (lds[1]) -> coalesced stores
  char* tb = lds[1];
  size_t prow = (size_t)b * kHW + (size_t)y * 256;
#pragma unroll
  for (int mf = 0; mf < 3; ++mf) {
    int oc0 = och * 48 + mf * 16 + g * 4;
    f32x4 bv;
#pragma unroll
    for (int r = 0; r < 4; ++r) bv[r] = bias[oc0 + r];
#pragma unroll
    for (int nf = 0; nf < 4; ++nf) {
      int pp = xq * 64 + nf * 16 + col;
      f32x4 v = acc[mf][nf] + bv;
      if (MODE == 0) {
#pragma unroll
        for (int r = 0; r < 4; ++r) v[r] = fmaxf(v[r], 0.f);
      } else {
        size_t p = prow + x0 + pp;
        us4 a4 = *(const us4*)(attn + ((size_t)(och * 3 + mf) * kP + p) * 16 + g * 4);
#pragma unroll
        for (int r = 0; r < 4; ++r) v[r] += bf2f(a4[r]);
      }
      us4 o;
#pragma unroll
      for (int r = 0; r < 4; ++r) o[r] = f2bf(v[r]);
      *(us4*)(tb + pp * 208 + oc0 * 2) = o;
    }
  }
  __syncthreads();
  {
    int pp = t >> 1, half = t & 1;
    const char* src = tb + pp * 208 + half * 96;
    us8 o0 = *(const us8*)(src);
    us8 o1 = *(const us8*)(src + 16);
    us8 o2 = *(const us8*)(src + 32);
    us8 o3 = *(const us8*)(src + 48);
    us8 o4 = *(const us8*)(src + 64);
    us8 o5 = *(const us8*)(src + 80);
    unsigned short* dst = O_ + (prow + x0) * 96 + (size_t)t * 48;
    *(us8*)(dst)      = o0;
    *(us8*)(dst + 8)  = o1;
    *(us8*)(dst + 16) = o2;
    *(us8*)(dst + 24) = o3;
    *(us8*)(dst + 32) = o4;
    *(us8*)(dst + 40) = o5;
  }
}

// ---------------- final projection -> d_out NCHW fp32 ------------------------
__global__ __launch_bounds__(256, 2) void proj_gemm(
    const unsigned short* __restrict__ Wph, const unsigned short* __restrict__ Wpl,
    const unsigned short* __restrict__ S_, const float* __restrict__ bias,
    float* __restrict__ out) {
  int t = threadIdx.x, wv = t >> 6, lane = t & 63;
  size_t px0 = (size_t)blockIdx.x * 256 + wv * 64;
  int col = lane & 15, g = lane >> 4;
  f32x4 acc[6][4];
#pragma unroll
  for (int m = 0; m < 6; ++m)
#pragma unroll
    for (int n = 0; n < 4; ++n) acc[m][n] = (f32x4)0.f;
  const char* aH = (const char*)Wph + (size_t)(col * 96 + g * 8) * 2;
  const char* aL = (const char*)Wpl + (size_t)(col * 96 + g * 8) * 2;
  const char* bH = (const char*)S_ + ((px0 + col) * 96 + g * 8) * 2;
#pragma unroll
  for (int ks = 0; ks < 3; ++ks) {
    short8 Ah[6], Al[6], Bf[4];
#pragma unroll
    for (int mf = 0; mf < 6; ++mf) {
      Ah[mf] = *(const short8*)(aH + (size_t)(mf * 16 * 96 + ks * 32) * 2);
      Al[mf] = *(const short8*)(aL + (size_t)(mf * 16 * 96 + ks * 32) * 2);
    }
#pragma unroll
    for (int nf = 0; nf < 4; ++nf)
      Bf[nf] = *(const short8*)(bH + (size_t)(nf * 16 * 96 + ks * 32) * 2);
#pragma unroll
    for (int mf = 0; mf < 6; ++mf)
#pragma unroll
      for (int nf = 0; nf < 4; ++nf) {
        acc[mf][nf] = __builtin_amdgcn_mfma_f32_16x16x32_bf16(Ah[mf], Bf[nf], acc[mf][nf], 0, 0, 0);
        acc[mf][nf] = __builtin_amdgcn_mfma_f32_16x16x32_bf16(Al[mf], Bf[nf], acc[mf][nf], 0, 0, 0);
      }
  }
#pragma unroll
  for (int mf = 0; mf < 6; ++mf) {
    int oc0 = mf * 16 + g * 4;
#pragma unroll
    for (int nf = 0; nf < 4; ++nf) {
      size_t p = px0 + nf * 16 + col;
      size_t bb = p >> 16, pix = p & 65535;
      f32x4 v = acc[mf][nf];
#pragma unroll
      for (int r = 0; r < 4; ++r)
        out[(bb * 96 + oc0 + r) * (size_t)kHW + pix] = v[r] + bias[oc0 + r];
    }
  }
}

extern "C" void kernel_launch(void* const* d_in, const int* in_sizes, int n_in,
                              void* d_out, int out_size, void* d_ws, size_t ws_size,
                              hipStream_t stream) {
  const float* X       = (const float*)d_in[0];
  const float* V_w     = (const float*)d_in[1];
  const float* V_b     = (const float*)d_in[2];
  const float* QK_w    = (const float*)d_in[3];
  const float* QK_b    = (const float*)d_in[4];
  const float* meta_w1 = (const float*)d_in[5];
  const float* meta_b1 = (const float*)d_in[6];
  const float* meta_w2 = (const float*)d_in[7];
  const float* meta_b2 = (const float*)d_in[8];
  const float* conv1_w = (const float*)d_in[9];
  const float* conv1_b = (const float*)d_in[10];
  const float* conv2_w = (const float*)d_in[11];
  const float* conv2_b = (const float*)d_in[12];
  const float* proj_w  = (const float*)d_in[13];
  const float* proj_b  = (const float*)d_in[14];
  float* out = (float*)d_out;

  char* w = (char*)d_ws;
  const size_t PLANE = (size_t)kP * 96 * 2;      // 50,331,648 B
  unsigned short* Xh = (unsigned short*)(w + 0 * PLANE);
  unsigned short* Qp = (unsigned short*)(w + 1 * PLANE);
  unsigned short* Kp = (unsigned short*)(w + 2 * PLANE);
  unsigned short* Vr = (unsigned short*)(w + 3 * PLANE);
  float* bias_tab    = (float*)(w + 4 * PLANE);
  unsigned short* Wqh = (unsigned short*)(w + 4 * PLANE + 98304);
  unsigned short* Wql = Wqh + 27648;
  unsigned short* W1h = Wql + 27648;
  unsigned short* W2h = W1h + 82944;
  unsigned short* Wph = W2h + 82944;
  unsigned short* Wpl = Wph + 9216;
  // stream-ordered aliases
  unsigned short* T1r = Xh;            // X dead after qkv_gemm
  unsigned short* S2r = Qp;            // Q dead after attn
  unsigned short* attnB = (unsigned short*)out;  // d_out as bf16 head-planar scratch

  bias_kernel<<<dim3(64), dim3(64), 0, stream>>>(meta_w1, meta_b1, meta_w2, meta_b2, bias_tab);
  prep_weights<<<dim3(324), dim3(256), 0, stream>>>(QK_w, V_w, conv1_w, conv2_w, proj_w,
                                                    Wqh, Wql, W1h, W2h, Wph, Wpl);
  split_x<<<dim3(4096), dim3(256), 0, stream>>>(X, Xh);
  qkv_gemm<<<dim3(1024), dim3(256), 0, stream>>>(Wqh, Wql, Xh, QK_b, V_b, Qp, Kp, Vr);
  attn_mfma<<<dim3(1024, 6), dim3(256), 0, stream>>>(Qp, Kp, Vr, bias_tab, attnB);
  conv_gl<0><<<dim3(2048), dim3(256), 0, stream>>>(W1h, Vr, conv1_b, nullptr, T1r);
  conv_gl<1><<<dim3(2048), dim3(256), 0, stream>>>(W2h, T1r, conv2_b, attnB, S2r);
  proj_gemm<<<dim3(1024), dim3(256), 0, stream>>>(Wph, Wpl, S2r, proj_b, out);
}

// Round 13
// 366.424 us; speedup vs baseline: 1.8489x; 1.1807x over previous
//
#include <hip/hip_runtime.h>
#include <cmath>

typedef short  short8 __attribute__((ext_vector_type(8)));
typedef float  f32x4  __attribute__((ext_vector_type(4)));
typedef unsigned short us8 __attribute__((ext_vector_type(8)));
typedef unsigned short us4 __attribute__((ext_vector_type(4)));

constexpr int kHW = 65536;           // 256*256
constexpr int kP  = 262144;          // 4 * kHW total pixels

__device__ __forceinline__ unsigned short f2bf(float x) {
  unsigned u = __builtin_bit_cast(unsigned, x);
  u += 0x7fffu + ((u >> 16) & 1u);
  return (unsigned short)(u >> 16);
}
__device__ __forceinline__ float bf2f(unsigned short h) {
  unsigned u = ((unsigned)h) << 16;
  return __builtin_bit_cast(float, u);
}
__device__ __forceinline__ void split2(float v, unsigned short& h, unsigned short& l) {
  unsigned short hh = f2bf(v);
  h = hh;
  l = f2bf(v - bf2f(hh));
}
__device__ __forceinline__ void gload16(const void* g, void* l) {
  __builtin_amdgcn_global_load_lds(
      (const __attribute__((address_space(1))) void*)g,
      (__attribute__((address_space(3))) void*)l, 16, 0, 0);
}

// ---------------- bias table: bias_tab[h][i][j], h<6, i,j<64 ----------------
__global__ void bias_kernel(const float* __restrict__ w1, const float* __restrict__ b1,
                            const float* __restrict__ w2, const float* __restrict__ b2,
                            float* __restrict__ bias_tab) {
  int i = blockIdx.x;
  int j = threadIdx.x;
  float dy = (float)((i >> 3) - (j >> 3));
  float dx = (float)((i & 7) - (j & 7));
  float r0 = copysignf(log1pf(fabsf(dy)), dy);
  float r1 = copysignf(log1pf(fabsf(dx)), dx);
  float acc[6];
#pragma unroll
  for (int h = 0; h < 6; ++h) acc[h] = b2[h];
  for (int t = 0; t < 256; ++t) {
    float hv = fmaf(r0, w1[t], fmaf(r1, w1[256 + t], b1[t]));
    hv = fmaxf(hv, 0.f);
#pragma unroll
    for (int h = 0; h < 6; ++h) acc[h] = fmaf(hv, w2[t * 6 + h], acc[h]);
  }
#pragma unroll
  for (int h = 0; h < 6; ++h) bias_tab[h * 4096 + i * 64 + j] = acc[h];
}

// ---------------- weight prep ------------------------------------------------
__global__ void prep_weights(const float* __restrict__ qk_w, const float* __restrict__ v_w,
                             const float* __restrict__ c1w, const float* __restrict__ c2w,
                             const float* __restrict__ pjw,
                             unsigned short* __restrict__ Wqh, unsigned short* __restrict__ Wql,
                             unsigned short* __restrict__ W1h,
                             unsigned short* __restrict__ W2h,
                             unsigned short* __restrict__ Wph, unsigned short* __restrict__ Wpl) {
  int i = blockIdx.x * 256 + threadIdx.x;
  if (i < 27648) {
    float v = (i < 18432) ? qk_w[i] : v_w[i - 18432];
    split2(v, Wqh[i], Wql[i]);
  }
  if (i < 82944) {
    int dlt = i / 9216;
    int oc  = (i / 96) % 96;
    int ic  = i % 96;
    int src = (oc * 96 + ic) * 9 + dlt;
    W1h[i] = f2bf(c1w[src]);
    W2h[i] = f2bf(c2w[src]);
  }
  if (i < 9216) split2(pjw[i], Wph[i], Wpl[i]);
}

// ---------------- X: NCHW fp32 -> NHWC bf16 (hi only) -----------------------
__global__ __launch_bounds__(256) void split_x(const float* __restrict__ X,
                                               unsigned short* __restrict__ Xh) {
  __shared__ float tile[96][65];
  int t = threadIdx.x;
  size_t p0 = (size_t)blockIdx.x * 64;
  int b = (int)(p0 >> 16), pix = (int)(p0 & 65535);
  const float* xb = X + (size_t)b * 96 * kHW + pix;
#pragma unroll
  for (int i = 0; i < 24; ++i) {
    int ic = (t >> 6) + i * 4;
    tile[ic][t & 63] = xb[(size_t)ic * kHW + (t & 63)];
  }
  __syncthreads();
  int px = t >> 2;
  size_t outbase = (p0 + px) * 96;
#pragma unroll
  for (int cc = 0; cc < 3; ++cc) {
    int c = (t & 3) + cc * 4;
    us8 h8;
#pragma unroll
    for (int j = 0; j < 8; ++j) h8[j] = f2bf(tile[c * 8 + j][px]);
    *(us8*)(Xh + outbase + c * 8) = h8;
  }
}

// ---------------- merged QKV GEMM: X read once; Q,K,V all head-planar -------
__global__ __launch_bounds__(256, 2) void qkv_gemm(
    const unsigned short* __restrict__ Wqh, const unsigned short* __restrict__ Wql,
    const unsigned short* __restrict__ Xh,
    const float* __restrict__ qk_b, const float* __restrict__ v_b,
    unsigned short* __restrict__ Qp, unsigned short* __restrict__ Kp,
    unsigned short* __restrict__ Vp) {
  int t = threadIdx.x, wv = t >> 6, lane = t & 63;
  size_t px0 = (size_t)blockIdx.x * 256 + wv * 64;
  int col = lane & 15, g = lane >> 4;

  const char* bH = (const char*)Xh + ((px0 + col) * 96 + g * 8) * 2;
  short8 Bh[3][4];
#pragma unroll
  for (int ks = 0; ks < 3; ++ks)
#pragma unroll
    for (int nf = 0; nf < 4; ++nf)
      Bh[ks][nf] = *(const short8*)(bH + (size_t)(nf * 16 * 96 + ks * 32) * 2);

#pragma unroll 1
  for (int z = 0; z < 3; ++z) {
    f32x4 acc[6][4];
#pragma unroll
    for (int m = 0; m < 6; ++m)
#pragma unroll
      for (int n = 0; n < 4; ++n) acc[m][n] = (f32x4)0.f;
    const char* aH = (const char*)(Wqh + z * 9216) + (size_t)(col * 96 + g * 8) * 2;
    const char* aL = (const char*)(Wql + z * 9216) + (size_t)(col * 96 + g * 8) * 2;
#pragma unroll
    for (int ks = 0; ks < 3; ++ks) {
      short8 Ah[6], Al[6];
#pragma unroll
      for (int mf = 0; mf < 6; ++mf) {
        Ah[mf] = *(const short8*)(aH + (size_t)(mf * 16 * 96 + ks * 32) * 2);
        Al[mf] = *(const short8*)(aL + (size_t)(mf * 16 * 96 + ks * 32) * 2);
      }
#pragma unroll
      for (int mf = 0; mf < 6; ++mf)
#pragma unroll
        for (int nf = 0; nf < 4; ++nf) {
          acc[mf][nf] = __builtin_amdgcn_mfma_f32_16x16x32_bf16(Ah[mf], Bh[ks][nf], acc[mf][nf], 0, 0, 0);
          acc[mf][nf] = __builtin_amdgcn_mfma_f32_16x16x32_bf16(Al[mf], Bh[ks][nf], acc[mf][nf], 0, 0, 0);
        }
    }
    const float* bias = (z == 0) ? qk_b : (z == 1 ? qk_b + 96 : v_b);
    float scale = (z == 0) ? 0.25f : 1.f;
    unsigned short* dst = (z == 0) ? Qp : (z == 1 ? Kp : Vp);
#pragma unroll
    for (int mf = 0; mf < 6; ++mf) {
      int oc0 = mf * 16 + g * 4;
      f32x4 bv;
#pragma unroll
      for (int r = 0; r < 4; ++r) bv[r] = bias[oc0 + r];
#pragma unroll
      for (int nf = 0; nf < 4; ++nf) {
        size_t p = px0 + nf * 16 + col;
        f32x4 v = (acc[mf][nf] + bv) * scale;
        us4 o;
#pragma unroll
        for (int r = 0; r < 4; ++r) o[r] = f2bf(v[r]);
        *(us4*)(dst + ((size_t)mf * kP + p) * 16 + g * 4) = o;   // head-planar
      }
    }
  }
}

// ---------------- attention via MFMA (wave = one window-head) ---------------
__global__ __launch_bounds__(256) void attn_mfma(
    const unsigned short* __restrict__ Qp, const unsigned short* __restrict__ Kp,
    const unsigned short* __restrict__ Vp, const float* __restrict__ bias_tab,
    unsigned short* __restrict__ out) {
  __shared__ unsigned short PT[4][64 * 72];   // per-wave P[q][k] bf16; reused as O[q][d]
  __shared__ unsigned short VT[4][16 * 72];   // per-wave V^T[d][k] bf16
  __shared__ float rls[4][64];                // per-wave 1/sum per q

  int t = threadIdx.x;
  int wv = t >> 6, lane = t & 63;
  int l15 = lane & 15, g = lane >> 4;
  int h = blockIdx.y;
  int wid = blockIdx.x * 4 + wv;
  int b = wid >> 10, wy = (wid >> 5) & 31, wx = wid & 31;
  size_t p0 = ((size_t)b << 16) + (size_t)wy * 8 * 256 + (size_t)wx * 8;
  const float* bt = bias_tab + h * 4096;

  f32x4 acc[4][4];   // [kf][qf]  C-init = bias
#pragma unroll
  for (int kf = 0; kf < 4; ++kf)
#pragma unroll
    for (int qf = 0; qf < 4; ++qf)
      acc[kf][qf] = *(const f32x4*)(bt + (qf * 16 + l15) * 64 + kf * 16 + g * 4);

  short8 Af[4], Bf[4];
#pragma unroll
  for (int f = 0; f < 4; ++f) {
    int kk = f * 16 + l15;
    size_t pk = p0 + (size_t)(kk >> 3) * 256 + (kk & 7);
    if (g < 2) {
      Af[f] = *(const short8*)(Kp + ((size_t)h * kP + pk) * 16 + g * 8);
      Bf[f] = *(const short8*)(Qp + ((size_t)h * kP + pk) * 16 + g * 8);
    } else {
      Af[f] = (short8)0;
      Bf[f] = (short8)0;
    }
  }

  // stage V^T[d][k] (own window pixel's 16 channels, head-planar V)
  {
    size_t pv = p0 + (size_t)(lane >> 3) * 256 + (lane & 7);
    const unsigned short* vp = Vp + ((size_t)h * kP + pv) * 16;
    us8 v0 = *(const us8*)(vp), v1 = *(const us8*)(vp + 8);
    unsigned short* vt = VT[wv];
#pragma unroll
    for (int d = 0; d < 8; ++d) {
      vt[d * 72 + lane]       = v0[d];
      vt[(d + 8) * 72 + lane] = v1[d];
    }
  }

#pragma unroll
  for (int kf = 0; kf < 4; ++kf)
#pragma unroll
    for (int qf = 0; qf < 4; ++qf)
      acc[kf][qf] = __builtin_amdgcn_mfma_f32_16x16x32_bf16(Af[kf], Bf[qf], acc[kf][qf], 0, 0, 0);

#pragma unroll
  for (int qf = 0; qf < 4; ++qf) {
    float m = acc[0][qf][0];
#pragma unroll
    for (int kf = 0; kf < 4; ++kf)
#pragma unroll
      for (int r = 0; r < 4; ++r) m = fmaxf(m, acc[kf][qf][r]);
    m = fmaxf(m, __shfl_xor(m, 16));
    m = fmaxf(m, __shfl_xor(m, 32));
    float sum = 0.f;
#pragma unroll
    for (int kf = 0; kf < 4; ++kf)
#pragma unroll
      for (int r = 0; r < 4; ++r) {
        float pe = __expf(acc[kf][qf][r] - m);
        acc[kf][qf][r] = pe;
        sum += pe;
      }
    sum += __shfl_xor(sum, 16);
    sum += __shfl_xor(sum, 32);
    if (g == 0) rls[wv][qf * 16 + l15] = 1.f / sum;
  }

  unsigned short* pt = PT[wv];
#pragma unroll
  for (int qf = 0; qf < 4; ++qf)
#pragma unroll
    for (int kf = 0; kf < 4; ++kf) {
      us4 pb;
#pragma unroll
      for (int r = 0; r < 4; ++r) pb[r] = f2bf(acc[kf][qf][r]);
      *(us4*)&pt[(qf * 16 + l15) * 72 + kf * 16 + g * 4] = pb;
    }

  short8 Pa[4][2], Vb[2];
#pragma unroll
  for (int qf = 0; qf < 4; ++qf)
#pragma unroll
    for (int kc = 0; kc < 2; ++kc)
      Pa[qf][kc] = *(const short8*)&pt[(qf * 16 + l15) * 72 + kc * 32 + g * 8];
#pragma unroll
  for (int kc = 0; kc < 2; ++kc)
    Vb[kc] = *(const short8*)&VT[wv][l15 * 72 + kc * 32 + g * 8];
  f32x4 o[4];
#pragma unroll
  for (int qf = 0; qf < 4; ++qf) {
    o[qf] = (f32x4)0.f;
#pragma unroll
    for (int kc = 0; kc < 2; ++kc)
      o[qf] = __builtin_amdgcn_mfma_f32_16x16x32_bf16(Pa[qf][kc], Vb[kc], o[qf], 0, 0, 0);
  }

#pragma unroll
  for (int qf = 0; qf < 4; ++qf) {
    f32x4 rv = *(const f32x4*)&rls[wv][qf * 16 + g * 4];
#pragma unroll
    for (int r = 0; r < 4; ++r)
      pt[(qf * 16 + g * 4 + r) * 72 + l15] = f2bf(o[qf][r] * rv[r]);
  }
  {
    int q = lane;
    us8 o0 = *(const us8*)&pt[q * 72];
    us8 o1 = *(const us8*)&pt[q * 72 + 8];
    size_t pq = p0 + (size_t)(q >> 3) * 256 + (q & 7);
    unsigned short* op = out + ((size_t)h * kP + pq) * 16;
    *(us8*)(op)     = o0;
    *(us8*)(op + 8) = o1;
  }
}

// ---------------- conv: single-phase, 3 LDS slots, straight-line MFMA -------
// Slot layout: 16B chunk L = ks*520 + gp*130 + pp at byte L*16 (linear dst).
// Source pre-swizzle: chunk carries (pixel pp, chan-8-block c8 = ks*4+(gp^(pp&3)))
// MODE 0: input head-planar V ([h][p][16]); MODE 1: input row-major [p][96].
constexpr int kChunks = 1560;        // 130 px * 12 chunks
constexpr int kSlotB  = 26624;       // >= max(24960 staging, 128*208 transpose)

__device__ __forceinline__ void stage_rows(const char* __restrict__ rowbase,
                                           char* slot, const int (&off)[7], int t) {
  int wvbase = t & 192;
#pragma unroll
  for (int i = 0; i < 7; ++i) {
    if (i < 6 || t < 24)
      gload16(rowbase + off[i], slot + (i * 256 + wvbase) * 16);
  }
}

__device__ __forceinline__ void conv_dy(
    const char* __restrict__ lds, const unsigned short* __restrict__ Wh,
    int tap0, int och, int xq, int col, int g, f32x4 (&acc)[3][4]) {
#pragma unroll
  for (int dx = 0; dx < 3; ++dx) {
    const char* ah = (const char*)Wh + ((size_t)(tap0 + dx) * 9216 + och * 4608 + col * 96 + g * 8) * 2;
    int ppb = xq * 64 + col + dx;
#pragma unroll
    for (int ks = 0; ks < 3; ++ks) {
      short8 Ah[3], Bf[4];
#pragma unroll
      for (int mf = 0; mf < 3; ++mf)
        Ah[mf] = *(const short8*)(ah + (size_t)(mf * 16 * 96 + ks * 32) * 2);
#pragma unroll
      for (int nf = 0; nf < 4; ++nf) {
        int pp = ppb + nf * 16;
        Bf[nf] = *(const short8*)(lds + ks * 8320 + ((g ^ (pp & 3)) * 2080) + pp * 16);
      }
#pragma unroll
      for (int mf = 0; mf < 3; ++mf)
#pragma unroll
        for (int nf = 0; nf < 4; ++nf)
          acc[mf][nf] = __builtin_amdgcn_mfma_f32_16x16x32_bf16(Ah[mf], Bf[nf], acc[mf][nf], 0, 0, 0);
    }
  }
}

template <int MODE>
__global__ __launch_bounds__(256, 2) void conv_gl(
    const unsigned short* __restrict__ Wh,
    const unsigned short* __restrict__ B_, const float* __restrict__ bias,
    const unsigned short* __restrict__ attn, unsigned short* __restrict__ O_) {
  __shared__ char lds[3][kSlotB];
  int t = threadIdx.x, wv = t >> 6, lane = t & 63;
  int col = lane & 15, g = lane >> 4;
  int och = wv >> 1, xq = wv & 1;
  int bid = blockIdx.x;
  int g8 = (bid & 7) * 256 + (bid >> 3);   // XCD-chunked
  int xh = g8 & 1;
  int ry = g8 >> 1;
  int b = ry >> 8, y = ry & 255;
  int x0 = xh * 128;

  // per-thread pre-swizzled source offsets (bytes) for the 7 stage issues
  int off[7];
#pragma unroll
  for (int i = 0; i < 7; ++i) {
    int idx = i * 256 + t;
    int ks = idx / 520;
    int rem = idx - ks * 520;
    int gp = rem / 130;
    int pp = rem - gp * 130;
    int c8 = ks * 4 + (gp ^ (pp & 3));
    int xx = x0 - 1 + pp;
    xx = xx < 0 ? 1 : (xx > 255 ? 254 : xx);
    if (MODE == 0)
      off[i] = (((c8 >> 1) * kP + xx) * 16 + (c8 & 1) * 8) * 2;   // head-planar
    else
      off[i] = (xx * 96 + c8 * 8) * 2;                            // row-major
  }

  const size_t rowBytes = (MODE == 0) ? (size_t)256 * 32 : (size_t)256 * 192;
  const char* Bbase = (const char*)B_ + (size_t)b * kHW * ((MODE == 0) ? 32 : 192);
  int ym = (y == 0) ? 1 : y - 1;
  int yp = (y == 255) ? 254 : y + 1;

  // stage all 3 rows, one drain
  stage_rows(Bbase + (size_t)ym * rowBytes, lds[0], off, t);
  stage_rows(Bbase + (size_t)y  * rowBytes, lds[1], off, t);
  stage_rows(Bbase + (size_t)yp * rowBytes, lds[2], off, t);
  __syncthreads();

  f32x4 acc[3][4];
#pragma unroll
  for (int m = 0; m < 3; ++m)
#pragma unroll
    for (int n = 0; n < 4; ++n) acc[m][n] = (f32x4)0.f;

  conv_dy(lds[0], Wh, 0, och, xq, col, g, acc);
  conv_dy(lds[1], Wh, 3, och, xq, col, g, acc);
  conv_dy(lds[2], Wh, 6, och, xq, col, g, acc);
  __syncthreads();                         // all waves done reading slot 0

  // epilogue: transpose through slot 0 -> coalesced stores
  char* tb = lds[0];
  size_t prow = (size_t)b * kHW + (size_t)y * 256;
#pragma unroll
  for (int mf = 0; mf < 3; ++mf) {
    int oc0 = och * 48 + mf * 16 + g * 4;
    f32x4 bv;
#pragma unroll
    for (int r = 0; r < 4; ++r) bv[r] = bias[oc0 + r];
#pragma unroll
    for (int nf = 0; nf < 4; ++nf) {
      int pp = xq * 64 + nf * 16 + col;
      f32x4 v = acc[mf][nf] + bv;
      if (MODE == 0) {
#pragma unroll
        for (int r = 0; r < 4; ++r) v[r] = fmaxf(v[r], 0.f);
      } else {
        size_t p = prow + x0 + pp;
        us4 a4 = *(const us4*)(attn + ((size_t)(och * 3 + mf) * kP + p) * 16 + g * 4);
#pragma unroll
        for (int r = 0; r < 4; ++r) v[r] += bf2f(a4[r]);
      }
      us4 o;
#pragma unroll
      for (int r = 0; r < 4; ++r) o[r] = f2bf(v[r]);
      *(us4*)(tb + pp * 208 + oc0 * 2) = o;
    }
  }
  __syncthreads();
  {
    int pp = t >> 1, half = t & 1;
    const char* src = tb + pp * 208 + half * 96;
    us8 o0 = *(const us8*)(src);
    us8 o1 = *(const us8*)(src + 16);
    us8 o2 = *(const us8*)(src + 32);
    us8 o3 = *(const us8*)(src + 48);
    us8 o4 = *(const us8*)(src + 64);
    us8 o5 = *(const us8*)(src + 80);
    unsigned short* dst = O_ + (prow + x0) * 96 + (size_t)t * 48;
    *(us8*)(dst)      = o0;
    *(us8*)(dst + 8)  = o1;
    *(us8*)(dst + 16) = o2;
    *(us8*)(dst + 24) = o3;
    *(us8*)(dst + 32) = o4;
    *(us8*)(dst + 40) = o5;
  }
}

// ---------------- final projection -> d_out NCHW fp32 ------------------------
__global__ __launch_bounds__(256, 2) void proj_gemm(
    const unsigned short* __restrict__ Wph, const unsigned short* __restrict__ Wpl,
    const unsigned short* __restrict__ S_, const float* __restrict__ bias,
    float* __restrict__ out) {
  int t = threadIdx.x, wv = t >> 6, lane = t & 63;
  size_t px0 = (size_t)blockIdx.x * 256 + wv * 64;
  int col = lane & 15, g = lane >> 4;
  f32x4 acc[6][4];
#pragma unroll
  for (int m = 0; m < 6; ++m)
#pragma unroll
    for (int n = 0; n < 4; ++n) acc[m][n] = (f32x4)0.f;
  const char* aH = (const char*)Wph + (size_t)(col * 96 + g * 8) * 2;
  const char* aL = (const char*)Wpl + (size_t)(col * 96 + g * 8) * 2;
  const char* bH = (const char*)S_ + ((px0 + col) * 96 + g * 8) * 2;
#pragma unroll
  for (int ks = 0; ks < 3; ++ks) {
    short8 Ah[6], Al[6], Bf[4];
#pragma unroll
    for (int mf = 0; mf < 6; ++mf) {
      Ah[mf] = *(const short8*)(aH + (size_t)(mf * 16 * 96 + ks * 32) * 2);
      Al[mf] = *(const short8*)(aL + (size_t)(mf * 16 * 96 + ks * 32) * 2);
    }
#pragma unroll
    for (int nf = 0; nf < 4; ++nf)
      Bf[nf] = *(const short8*)(bH + (size_t)(nf * 16 * 96 + ks * 32) * 2);
#pragma unroll
    for (int mf = 0; mf < 6; ++mf)
#pragma unroll
      for (int nf = 0; nf < 4; ++nf) {
        acc[mf][nf] = __builtin_amdgcn_mfma_f32_16x16x32_bf16(Ah[mf], Bf[nf], acc[mf][nf], 0, 0, 0);
        acc[mf][nf] = __builtin_amdgcn_mfma_f32_16x16x32_bf16(Al[mf], Bf[nf], acc[mf][nf], 0, 0, 0);
      }
  }
#pragma unroll
  for (int mf = 0; mf < 6; ++mf) {
    int oc0 = mf * 16 + g * 4;
#pragma unroll
    for (int nf = 0; nf < 4; ++nf) {
      size_t p = px0 + nf * 16 + col;
      size_t bb = p >> 16, pix = p & 65535;
      f32x4 v = acc[mf][nf];
#pragma unroll
      for (int r = 0; r < 4; ++r)
        out[(bb * 96 + oc0 + r) * (size_t)kHW + pix] = v[r] + bias[oc0 + r];
    }
  }
}

extern "C" void kernel_launch(void* const* d_in, const int* in_sizes, int n_in,
                              void* d_out, int out_size, void* d_ws, size_t ws_size,
                              hipStream_t stream) {
  const float* X       = (const float*)d_in[0];
  const float* V_w     = (const float*)d_in[1];
  const float* V_b     = (const float*)d_in[2];
  const float* QK_w    = (const float*)d_in[3];
  const float* QK_b    = (const float*)d_in[4];
  const float* meta_w1 = (const float*)d_in[5];
  const float* meta_b1 = (const float*)d_in[6];
  const float* meta_w2 = (const float*)d_in[7];
  const float* meta_b2 = (const float*)d_in[8];
  const float* conv1_w = (const float*)d_in[9];
  const float* conv1_b = (const float*)d_in[10];
  const float* conv2_w = (const float*)d_in[11];
  const float* conv2_b = (const float*)d_in[12];
  const float* proj_w  = (const float*)d_in[13];
  const float* proj_b  = (const float*)d_in[14];
  float* out = (float*)d_out;

  char* w = (char*)d_ws;
  const size_t PLANE = (size_t)kP * 96 * 2;      // 50,331,648 B
  unsigned short* Xh = (unsigned short*)(w + 0 * PLANE);
  unsigned short* Qp = (unsigned short*)(w + 1 * PLANE);
  unsigned short* Kp = (unsigned short*)(w + 2 * PLANE);
  unsigned short* Vp = (unsigned short*)(w + 3 * PLANE);
  float* bias_tab    = (float*)(w + 4 * PLANE);
  unsigned short* Wqh = (unsigned short*)(w + 4 * PLANE + 98304);
  unsigned short* Wql = Wqh + 27648;
  unsigned short* W1h = Wql + 27648;
  unsigned short* W2h = W1h + 82944;
  unsigned short* Wph = W2h + 82944;
  unsigned short* Wpl = Wph + 9216;
  // stream-ordered aliases
  unsigned short* T1r = Xh;            // X dead after qkv_gemm (row-major [p][96])
  unsigned short* S2r = Qp;            // Q dead after attn
  unsigned short* attnB = (unsigned short*)out;  // d_out as bf16 head-planar scratch

  bias_kernel<<<dim3(64), dim3(64), 0, stream>>>(meta_w1, meta_b1, meta_w2, meta_b2, bias_tab);
  prep_weights<<<dim3(324), dim3(256), 0, stream>>>(QK_w, V_w, conv1_w, conv2_w, proj_w,
                                                    Wqh, Wql, W1h, W2h, Wph, Wpl);
  split_x<<<dim3(4096), dim3(256), 0, stream>>>(X, Xh);
  qkv_gemm<<<dim3(1024), dim3(256), 0, stream>>>(Wqh, Wql, Xh, QK_b, V_b, Qp, Kp, Vp);
  attn_mfma<<<dim3(1024, 6), dim3(256), 0, stream>>>(Qp, Kp, Vp, bias_tab, attnB);
  conv_gl<0><<<dim3(2048), dim3(256), 0, stream>>>(W1h, Vp, conv1_b, nullptr, T1r);
  conv_gl<1><<<dim3(2048), dim3(256), 0, stream>>>(W2h, T1r, conv2_b, attnB, S2r);
  proj_gemm<<<dim3(1024), dim3(256), 0, stream>>>(Wph, Wpl, S2r, proj_b, out);
}

// Round 14
// 356.840 us; speedup vs baseline: 1.8985x; 1.0269x over previous
//
#include <hip/hip_runtime.h>
#include <cmath>

typedef short  short8 __attribute__((ext_vector_type(8)));
typedef float  f32x4  __attribute__((ext_vector_type(4)));
typedef unsigned short us8 __attribute__((ext_vector_type(8)));
typedef unsigned short us4 __attribute__((ext_vector_type(4)));

constexpr int kHW = 65536;           // 256*256
constexpr int kP  = 262144;          // 4 * kHW total pixels

__device__ __forceinline__ unsigned short f2bf(float x) {
  unsigned u = __builtin_bit_cast(unsigned, x);
  u += 0x7fffu + ((u >> 16) & 1u);
  return (unsigned short)(u >> 16);
}
__device__ __forceinline__ float bf2f(unsigned short h) {
  unsigned u = ((unsigned)h) << 16;
  return __builtin_bit_cast(float, u);
}
__device__ __forceinline__ void split2(float v, unsigned short& h, unsigned short& l) {
  unsigned short hh = f2bf(v);
  h = hh;
  l = f2bf(v - bf2f(hh));
}
__device__ __forceinline__ void gload16(const void* g, void* l) {
  __builtin_amdgcn_global_load_lds(
      (const __attribute__((address_space(1))) void*)g,
      (__attribute__((address_space(3))) void*)l, 16, 0, 0);
}
#define CFENCE() asm volatile("" ::: "memory")
#define WAITVM7() asm volatile("s_waitcnt vmcnt(7)" ::: "memory")
#define WAITVM0() asm volatile("s_waitcnt vmcnt(0)" ::: "memory")
#define SBAR() __builtin_amdgcn_s_barrier()

// ---------------- bias table: bias_tab[h][i][j], h<6, i,j<64 ----------------
__global__ void bias_kernel(const float* __restrict__ w1, const float* __restrict__ b1,
                            const float* __restrict__ w2, const float* __restrict__ b2,
                            float* __restrict__ bias_tab) {
  int i = blockIdx.x;
  int j = threadIdx.x;
  float dy = (float)((i >> 3) - (j >> 3));
  float dx = (float)((i & 7) - (j & 7));
  float r0 = copysignf(log1pf(fabsf(dy)), dy);
  float r1 = copysignf(log1pf(fabsf(dx)), dx);
  float acc[6];
#pragma unroll
  for (int h = 0; h < 6; ++h) acc[h] = b2[h];
  for (int t = 0; t < 256; ++t) {
    float hv = fmaf(r0, w1[t], fmaf(r1, w1[256 + t], b1[t]));
    hv = fmaxf(hv, 0.f);
#pragma unroll
    for (int h = 0; h < 6; ++h) acc[h] = fmaf(hv, w2[t * 6 + h], acc[h]);
  }
#pragma unroll
  for (int h = 0; h < 6; ++h) bias_tab[h * 4096 + i * 64 + j] = acc[h];
}

// ---------------- weight prep ------------------------------------------------
__global__ void prep_weights(const float* __restrict__ qk_w, const float* __restrict__ v_w,
                             const float* __restrict__ c1w, const float* __restrict__ c2w,
                             const float* __restrict__ pjw,
                             unsigned short* __restrict__ Wqh, unsigned short* __restrict__ Wql,
                             unsigned short* __restrict__ W1h,
                             unsigned short* __restrict__ W2h,
                             unsigned short* __restrict__ Wph, unsigned short* __restrict__ Wpl) {
  int i = blockIdx.x * 256 + threadIdx.x;
  if (i < 27648) {
    float v = (i < 18432) ? qk_w[i] : v_w[i - 18432];
    split2(v, Wqh[i], Wql[i]);
  }
  if (i < 82944) {
    int dlt = i / 9216;
    int oc  = (i / 96) % 96;
    int ic  = i % 96;
    int src = (oc * 96 + ic) * 9 + dlt;
    W1h[i] = f2bf(c1w[src]);
    W2h[i] = f2bf(c2w[src]);
  }
  if (i < 9216) split2(pjw[i], Wph[i], Wpl[i]);
}

// ---------------- X: NCHW fp32 -> NHWC bf16 (hi only) -----------------------
__global__ __launch_bounds__(256) void split_x(const float* __restrict__ X,
                                               unsigned short* __restrict__ Xh) {
  __shared__ float tile[96][65];
  int t = threadIdx.x;
  size_t p0 = (size_t)blockIdx.x * 64;
  int b = (int)(p0 >> 16), pix = (int)(p0 & 65535);
  const float* xb = X + (size_t)b * 96 * kHW + pix;
#pragma unroll
  for (int i = 0; i < 24; ++i) {
    int ic = (t >> 6) + i * 4;
    tile[ic][t & 63] = xb[(size_t)ic * kHW + (t & 63)];
  }
  __syncthreads();
  int px = t >> 2;
  size_t outbase = (p0 + px) * 96;
#pragma unroll
  for (int cc = 0; cc < 3; ++cc) {
    int c = (t & 3) + cc * 4;
    us8 h8;
#pragma unroll
    for (int j = 0; j < 8; ++j) h8[j] = f2bf(tile[c * 8 + j][px]);
    *(us8*)(Xh + outbase + c * 8) = h8;
  }
}

// ---------------- merged QKV GEMM: X read once; Q,K,V all head-planar -------
__global__ __launch_bounds__(256, 2) void qkv_gemm(
    const unsigned short* __restrict__ Wqh, const unsigned short* __restrict__ Wql,
    const unsigned short* __restrict__ Xh,
    const float* __restrict__ qk_b, const float* __restrict__ v_b,
    unsigned short* __restrict__ Qp, unsigned short* __restrict__ Kp,
    unsigned short* __restrict__ Vp) {
  int t = threadIdx.x, wv = t >> 6, lane = t & 63;
  size_t px0 = (size_t)blockIdx.x * 256 + wv * 64;
  int col = lane & 15, g = lane >> 4;

  const char* bH = (const char*)Xh + ((px0 + col) * 96 + g * 8) * 2;
  short8 Bh[3][4];
#pragma unroll
  for (int ks = 0; ks < 3; ++ks)
#pragma unroll
    for (int nf = 0; nf < 4; ++nf)
      Bh[ks][nf] = *(const short8*)(bH + (size_t)(nf * 16 * 96 + ks * 32) * 2);

#pragma unroll 1
  for (int z = 0; z < 3; ++z) {
    f32x4 acc[6][4];
#pragma unroll
    for (int m = 0; m < 6; ++m)
#pragma unroll
      for (int n = 0; n < 4; ++n) acc[m][n] = (f32x4)0.f;
    const char* aH = (const char*)(Wqh + z * 9216) + (size_t)(col * 96 + g * 8) * 2;
    const char* aL = (const char*)(Wql + z * 9216) + (size_t)(col * 96 + g * 8) * 2;
#pragma unroll
    for (int ks = 0; ks < 3; ++ks) {
      short8 Ah[6], Al[6];
#pragma unroll
      for (int mf = 0; mf < 6; ++mf) {
        Ah[mf] = *(const short8*)(aH + (size_t)(mf * 16 * 96 + ks * 32) * 2);
        Al[mf] = *(const short8*)(aL + (size_t)(mf * 16 * 96 + ks * 32) * 2);
      }
#pragma unroll
      for (int mf = 0; mf < 6; ++mf)
#pragma unroll
        for (int nf = 0; nf < 4; ++nf) {
          acc[mf][nf] = __builtin_amdgcn_mfma_f32_16x16x32_bf16(Ah[mf], Bh[ks][nf], acc[mf][nf], 0, 0, 0);
          acc[mf][nf] = __builtin_amdgcn_mfma_f32_16x16x32_bf16(Al[mf], Bh[ks][nf], acc[mf][nf], 0, 0, 0);
        }
    }
    const float* bias = (z == 0) ? qk_b : (z == 1 ? qk_b + 96 : v_b);
    float scale = (z == 0) ? 0.25f : 1.f;
    unsigned short* dst = (z == 0) ? Qp : (z == 1 ? Kp : Vp);
#pragma unroll
    for (int mf = 0; mf < 6; ++mf) {
      int oc0 = mf * 16 + g * 4;
      f32x4 bv;
#pragma unroll
      for (int r = 0; r < 4; ++r) bv[r] = bias[oc0 + r];
#pragma unroll
      for (int nf = 0; nf < 4; ++nf) {
        size_t p = px0 + nf * 16 + col;
        f32x4 v = (acc[mf][nf] + bv) * scale;
        us4 o;
#pragma unroll
        for (int r = 0; r < 4; ++r) o[r] = f2bf(v[r]);
        *(us4*)(dst + ((size_t)mf * kP + p) * 16 + g * 4) = o;   // head-planar
      }
    }
  }
}

// ---------------- attention via MFMA (wave = one window-head) ---------------
__global__ __launch_bounds__(256) void attn_mfma(
    const unsigned short* __restrict__ Qp, const unsigned short* __restrict__ Kp,
    const unsigned short* __restrict__ Vp, const float* __restrict__ bias_tab,
    unsigned short* __restrict__ out) {
  __shared__ unsigned short PT[4][64 * 72];   // per-wave P[q][k] bf16; reused as O[q][d]
  __shared__ unsigned short VT[4][16 * 72];   // per-wave V^T[d][k] bf16
  __shared__ float rls[4][64];                // per-wave 1/sum per q

  int t = threadIdx.x;
  int wv = t >> 6, lane = t & 63;
  int l15 = lane & 15, g = lane >> 4;
  int h = blockIdx.y;
  int wid = blockIdx.x * 4 + wv;
  int b = wid >> 10, wy = (wid >> 5) & 31, wx = wid & 31;
  size_t p0 = ((size_t)b << 16) + (size_t)wy * 8 * 256 + (size_t)wx * 8;
  const float* bt = bias_tab + h * 4096;

  f32x4 acc[4][4];   // [kf][qf]  C-init = bias
#pragma unroll
  for (int kf = 0; kf < 4; ++kf)
#pragma unroll
    for (int qf = 0; qf < 4; ++qf)
      acc[kf][qf] = *(const f32x4*)(bt + (qf * 16 + l15) * 64 + kf * 16 + g * 4);

  short8 Af[4], Bf[4];
#pragma unroll
  for (int f = 0; f < 4; ++f) {
    int kk = f * 16 + l15;
    size_t pk = p0 + (size_t)(kk >> 3) * 256 + (kk & 7);
    if (g < 2) {
      Af[f] = *(const short8*)(Kp + ((size_t)h * kP + pk) * 16 + g * 8);
      Bf[f] = *(const short8*)(Qp + ((size_t)h * kP + pk) * 16 + g * 8);
    } else {
      Af[f] = (short8)0;
      Bf[f] = (short8)0;
    }
  }

  // stage V^T[d][k] (own window pixel's 16 channels, head-planar V)
  {
    size_t pv = p0 + (size_t)(lane >> 3) * 256 + (lane & 7);
    const unsigned short* vp = Vp + ((size_t)h * kP + pv) * 16;
    us8 v0 = *(const us8*)(vp), v1 = *(const us8*)(vp + 8);
    unsigned short* vt = VT[wv];
#pragma unroll
    for (int d = 0; d < 8; ++d) {
      vt[d * 72 + lane]       = v0[d];
      vt[(d + 8) * 72 + lane] = v1[d];
    }
  }

#pragma unroll
  for (int kf = 0; kf < 4; ++kf)
#pragma unroll
    for (int qf = 0; qf < 4; ++qf)
      acc[kf][qf] = __builtin_amdgcn_mfma_f32_16x16x32_bf16(Af[kf], Bf[qf], acc[kf][qf], 0, 0, 0);

#pragma unroll
  for (int qf = 0; qf < 4; ++qf) {
    float m = acc[0][qf][0];
#pragma unroll
    for (int kf = 0; kf < 4; ++kf)
#pragma unroll
      for (int r = 0; r < 4; ++r) m = fmaxf(m, acc[kf][qf][r]);
    m = fmaxf(m, __shfl_xor(m, 16));
    m = fmaxf(m, __shfl_xor(m, 32));
    float sum = 0.f;
#pragma unroll
    for (int kf = 0; kf < 4; ++kf)
#pragma unroll
      for (int r = 0; r < 4; ++r) {
        float pe = __expf(acc[kf][qf][r] - m);
        acc[kf][qf][r] = pe;
        sum += pe;
      }
    sum += __shfl_xor(sum, 16);
    sum += __shfl_xor(sum, 32);
    if (g == 0) rls[wv][qf * 16 + l15] = 1.f / sum;
  }

  unsigned short* pt = PT[wv];
#pragma unroll
  for (int qf = 0; qf < 4; ++qf)
#pragma unroll
    for (int kf = 0; kf < 4; ++kf) {
      us4 pb;
#pragma unroll
      for (int r = 0; r < 4; ++r) pb[r] = f2bf(acc[kf][qf][r]);
      *(us4*)&pt[(qf * 16 + l15) * 72 + kf * 16 + g * 4] = pb;
    }

  short8 Pa[4][2], Vb[2];
#pragma unroll
  for (int qf = 0; qf < 4; ++qf)
#pragma unroll
    for (int kc = 0; kc < 2; ++kc)
      Pa[qf][kc] = *(const short8*)&pt[(qf * 16 + l15) * 72 + kc * 32 + g * 8];
#pragma unroll
  for (int kc = 0; kc < 2; ++kc)
    Vb[kc] = *(const short8*)&VT[wv][l15 * 72 + kc * 32 + g * 8];
  f32x4 o[4];
#pragma unroll
  for (int qf = 0; qf < 4; ++qf) {
    o[qf] = (f32x4)0.f;
#pragma unroll
    for (int kc = 0; kc < 2; ++kc)
      o[qf] = __builtin_amdgcn_mfma_f32_16x16x32_bf16(Pa[qf][kc], Vb[kc], o[qf], 0, 0, 0);
  }

#pragma unroll
  for (int qf = 0; qf < 4; ++qf) {
    f32x4 rv = *(const f32x4*)&rls[wv][qf * 16 + g * 4];
#pragma unroll
    for (int r = 0; r < 4; ++r)
      pt[(qf * 16 + g * 4 + r) * 72 + l15] = f2bf(o[qf][r] * rv[r]);
  }
  {
    int q = lane;
    us8 o0 = *(const us8*)&pt[q * 72];
    us8 o1 = *(const us8*)&pt[q * 72 + 8];
    size_t pq = p0 + (size_t)(q >> 3) * 256 + (q & 7);
    unsigned short* op = out + ((size_t)h * kP + pq) * 16;
    *(us8*)(op)     = o0;
    *(us8*)(op + 8) = o1;
  }
}

// ---------------- conv: 2-slot counted-vmcnt pipeline (T3/T4) ---------------
// Slot layout: 16B chunk L = ks*520 + gp*130 + pp at byte L*16 (linear dst).
// Source pre-swizzle: chunk carries (pixel pp, chan-8-block c8 = ks*4+(gp^(pp&3)))
// Each stage = exactly 7 gload16/wave (7th wave-uniform dst at chunk 1536+lane,
// duplicate-data across waves, pads harmless) -> uniform vmcnt counting.
// MODE 0: input head-planar V ([h][p][16]); MODE 1: input row-major [p][96].
constexpr int kSlotB = 26624;        // 1664 chunks >= 1600 staged; >= 128*208 transpose

__device__ __forceinline__ void stage_rows(const char* __restrict__ rowbase,
                                           char* slot, const int (&off)[7], int t) {
  int wvbase = t & 192;
#pragma unroll
  for (int i = 0; i < 6; ++i)
    gload16(rowbase + off[i], slot + (i * 256 + wvbase) * 16);
  gload16(rowbase + off[6], slot + 1536 * 16);   // wave-uniform dst, lane adds 16B
}

__device__ __forceinline__ void conv_dy(
    const char* __restrict__ lds, const unsigned short* __restrict__ Wh,
    int tap0, int och, int xq, int col, int g, f32x4 (&acc)[3][4]) {
#pragma unroll
  for (int dx = 0; dx < 3; ++dx) {
    const char* ah = (const char*)Wh + ((size_t)(tap0 + dx) * 9216 + och * 4608 + col * 96 + g * 8) * 2;
    int ppb = xq * 64 + col + dx;
#pragma unroll
    for (int ks = 0; ks < 3; ++ks) {
      short8 Ah[3], Bf[4];
#pragma unroll
      for (int mf = 0; mf < 3; ++mf)
        Ah[mf] = *(const short8*)(ah + (size_t)(mf * 16 * 96 + ks * 32) * 2);
#pragma unroll
      for (int nf = 0; nf < 4; ++nf) {
        int pp = ppb + nf * 16;
        Bf[nf] = *(const short8*)(lds + ks * 8320 + ((g ^ (pp & 3)) * 2080) + pp * 16);
      }
#pragma unroll
      for (int mf = 0; mf < 3; ++mf)
#pragma unroll
        for (int nf = 0; nf < 4; ++nf)
          acc[mf][nf] = __builtin_amdgcn_mfma_f32_16x16x32_bf16(Ah[mf], Bf[nf], acc[mf][nf], 0, 0, 0);
    }
  }
}

template <int MODE>
__global__ __launch_bounds__(256, 3) void conv_gl(
    const unsigned short* __restrict__ Wh,
    const unsigned short* __restrict__ B_, const float* __restrict__ bias,
    const unsigned short* __restrict__ attn, unsigned short* __restrict__ O_) {
  __shared__ char lds[2][kSlotB];
  int t = threadIdx.x, wv = t >> 6, lane = t & 63;
  int col = lane & 15, g = lane >> 4;
  int och = wv >> 1, xq = wv & 1;
  int bid = blockIdx.x;
  int g8 = (bid & 7) * 256 + (bid >> 3);   // XCD-chunked
  int xh = g8 & 1;
  int ry = g8 >> 1;
  int b = ry >> 8, y = ry & 255;
  int x0 = xh * 128;

  // per-thread pre-swizzled source offsets (bytes) for the 7 stage issues
  int off[7];
#pragma unroll
  for (int i = 0; i < 7; ++i) {
    int idx = (i < 6) ? (i * 256 + t) : (1536 + (t & 63));
    if (idx > 1559) idx = 1559;            // pad chunks: duplicate of last (unused)
    int ks = idx / 520;
    int rem = idx - ks * 520;
    int gp = rem / 130;
    int pp = rem - gp * 130;
    int c8 = ks * 4 + (gp ^ (pp & 3));
    int xx = x0 - 1 + pp;
    xx = xx < 0 ? 1 : (xx > 255 ? 254 : xx);
    if (MODE == 0)
      off[i] = (((c8 >> 1) * kP + xx) * 16 + (c8 & 1) * 8) * 2;   // head-planar
    else
      off[i] = (xx * 96 + c8 * 8) * 2;                            // row-major
  }

  const size_t rowBytes = (MODE == 0) ? (size_t)256 * 32 : (size_t)256 * 192;
  const char* Bbase = (const char*)B_ + (size_t)b * kHW * ((MODE == 0) ? 32 : 192);
  int ym = (y == 0) ? 1 : y - 1;
  int yp = (y == 255) ? 254 : y + 1;

  f32x4 acc[3][4];
#pragma unroll
  for (int m = 0; m < 3; ++m)
#pragma unroll
    for (int n = 0; n < 4; ++n) acc[m][n] = (f32x4)0.f;

  // counted-vmcnt pipeline: never drain to 0 until the last row
  stage_rows(Bbase + (size_t)ym * rowBytes, lds[0], off, t);   // 7 (oldest)
  CFENCE();
  stage_rows(Bbase + (size_t)y  * rowBytes, lds[1], off, t);   // 7
  WAITVM7(); SBAR();                       // slot0 complete across all waves
  conv_dy(lds[0], Wh, 0, och, xq, col, g, acc);
  SBAR();                                  // all waves done reading slot0
  stage_rows(Bbase + (size_t)yp * rowBytes, lds[0], off, t);   // 7 newest
  WAITVM7(); SBAR();                       // slot1 complete (older than newest 7)
  conv_dy(lds[1], Wh, 3, och, xq, col, g, acc);
  WAITVM0(); SBAR();                       // slot0 (y+1) complete
  conv_dy(lds[0], Wh, 6, och, xq, col, g, acc);

  // epilogue: transpose through slot1 (free after dy1) -> coalesced stores
  char* tb = lds[1];
  size_t prow = (size_t)b * kHW + (size_t)y * 256;
#pragma unroll
  for (int mf = 0; mf < 3; ++mf) {
    int oc0 = och * 48 + mf * 16 + g * 4;
    f32x4 bv;
#pragma unroll
    for (int r = 0; r < 4; ++r) bv[r] = bias[oc0 + r];
#pragma unroll
    for (int nf = 0; nf < 4; ++nf) {
      int pp = xq * 64 + nf * 16 + col;
      f32x4 v = acc[mf][nf] + bv;
      if (MODE == 0) {
#pragma unroll
        for (int r = 0; r < 4; ++r) v[r] = fmaxf(v[r], 0.f);
      } else {
        size_t p = prow + x0 + pp;
        us4 a4 = *(const us4*)(attn + ((size_t)(och * 3 + mf) * kP + p) * 16 + g * 4);
#pragma unroll
        for (int r = 0; r < 4; ++r) v[r] += bf2f(a4[r]);
      }
      us4 o;
#pragma unroll
      for (int r = 0; r < 4; ++r) o[r] = f2bf(v[r]);
      *(us4*)(tb + pp * 208 + oc0 * 2) = o;
    }
  }
  __syncthreads();
  {
    int pp = t >> 1, half = t & 1;
    const char* src = tb + pp * 208 + half * 96;
    us8 o0 = *(const us8*)(src);
    us8 o1 = *(const us8*)(src + 16);
    us8 o2 = *(const us8*)(src + 32);
    us8 o3 = *(const us8*)(src + 48);
    us8 o4 = *(const us8*)(src + 64);
    us8 o5 = *(const us8*)(src + 80);
    unsigned short* dst = O_ + (prow + x0) * 96 + (size_t)t * 48;
    *(us8*)(dst)      = o0;
    *(us8*)(dst + 8)  = o1;
    *(us8*)(dst + 16) = o2;
    *(us8*)(dst + 24) = o3;
    *(us8*)(dst + 32) = o4;
    *(us8*)(dst + 40) = o5;
  }
}

// ---------------- final projection -> d_out NCHW fp32 ------------------------
__global__ __launch_bounds__(256, 2) void proj_gemm(
    const unsigned short* __restrict__ Wph, const unsigned short* __restrict__ Wpl,
    const unsigned short* __restrict__ S_, const float* __restrict__ bias,
    float* __restrict__ out) {
  int t = threadIdx.x, wv = t >> 6, lane = t & 63;
  size_t px0 = (size_t)blockIdx.x * 256 + wv * 64;
  int col = lane & 15, g = lane >> 4;
  f32x4 acc[6][4];
#pragma unroll
  for (int m = 0; m < 6; ++m)
#pragma unroll
    for (int n = 0; n < 4; ++n) acc[m][n] = (f32x4)0.f;
  const char* aH = (const char*)Wph + (size_t)(col * 96 + g * 8) * 2;
  const char* aL = (const char*)Wpl + (size_t)(col * 96 + g * 8) * 2;
  const char* bH = (const char*)S_ + ((px0 + col) * 96 + g * 8) * 2;
#pragma unroll
  for (int ks = 0; ks < 3; ++ks) {
    short8 Ah[6], Al[6], Bf[4];
#pragma unroll
    for (int mf = 0; mf < 6; ++mf) {
      Ah[mf] = *(const short8*)(aH + (size_t)(mf * 16 * 96 + ks * 32) * 2);
      Al[mf] = *(const short8*)(aL + (size_t)(mf * 16 * 96 + ks * 32) * 2);
    }
#pragma unroll
    for (int nf = 0; nf < 4; ++nf)
      Bf[nf] = *(const short8*)(bH + (size_t)(nf * 16 * 96 + ks * 32) * 2);
#pragma unroll
    for (int mf = 0; mf < 6; ++mf)
#pragma unroll
      for (int nf = 0; nf < 4; ++nf) {
        acc[mf][nf] = __builtin_amdgcn_mfma_f32_16x16x32_bf16(Ah[mf], Bf[nf], acc[mf][nf], 0, 0, 0);
        acc[mf][nf] = __builtin_amdgcn_mfma_f32_16x16x32_bf16(Al[mf], Bf[nf], acc[mf][nf], 0, 0, 0);
      }
  }
#pragma unroll
  for (int mf = 0; mf < 6; ++mf) {
    int oc0 = mf * 16 + g * 4;
#pragma unroll
    for (int nf = 0; nf < 4; ++nf) {
      size_t p = px0 + nf * 16 + col;
      size_t bb = p >> 16, pix = p & 65535;
      f32x4 v = acc[mf][nf];
#pragma unroll
      for (int r = 0; r < 4; ++r)
        out[(bb * 96 + oc0 + r) * (size_t)kHW + pix] = v[r] + bias[oc0 + r];
    }
  }
}

extern "C" void kernel_launch(void* const* d_in, const int* in_sizes, int n_in,
                              void* d_out, int out_size, void* d_ws, size_t ws_size,
                              hipStream_t stream) {
  const float* X       = (const float*)d_in[0];
  const float* V_w     = (const float*)d_in[1];
  const float* V_b     = (const float*)d_in[2];
  const float* QK_w    = (const float*)d_in[3];
  const float* QK_b    = (const float*)d_in[4];
  const float* meta_w1 = (const float*)d_in[5];
  const float* meta_b1 = (const float*)d_in[6];
  const float* meta_w2 = (const float*)d_in[7];
  const float* meta_b2 = (const float*)d_in[8];
  const float* conv1_w = (const float*)d_in[9];
  const float* conv1_b = (const float*)d_in[10];
  const float* conv2_w = (const float*)d_in[11];
  const float* conv2_b = (const float*)d_in[12];
  const float* proj_w  = (const float*)d_in[13];
  const float* proj_b  = (const float*)d_in[14];
  float* out = (float*)d_out;

  char* w = (char*)d_ws;
  const size_t PLANE = (size_t)kP * 96 * 2;      // 50,331,648 B
  unsigned short* Xh = (unsigned short*)(w + 0 * PLANE);
  unsigned short* Qp = (unsigned short*)(w + 1 * PLANE);
  unsigned short* Kp = (unsigned short*)(w + 2 * PLANE);
  unsigned short* Vp = (unsigned short*)(w + 3 * PLANE);
  float* bias_tab    = (float*)(w + 4 * PLANE);
  unsigned short* Wqh = (unsigned short*)(w + 4 * PLANE + 98304);
  unsigned short* Wql = Wqh + 27648;
  unsigned short* W1h = Wql + 27648;
  unsigned short* W2h = W1h + 82944;
  unsigned short* Wph = W2h + 82944;
  unsigned short* Wpl = Wph + 9216;
  // stream-ordered aliases
  unsigned short* T1r = Xh;            // X dead after qkv_gemm (row-major [p][96])
  unsigned short* S2r = Qp;            // Q dead after attn
  unsigned short* attnB = (unsigned short*)out;  // d_out as bf16 head-planar scratch

  bias_kernel<<<dim3(64), dim3(64), 0, stream>>>(meta_w1, meta_b1, meta_w2, meta_b2, bias_tab);
  prep_weights<<<dim3(324), dim3(256), 0, stream>>>(QK_w, V_w, conv1_w, conv2_w, proj_w,
                                                    Wqh, Wql, W1h, W2h, Wph, Wpl);
  split_x<<<dim3(4096), dim3(256), 0, stream>>>(X, Xh);
  qkv_gemm<<<dim3(1024), dim3(256), 0, stream>>>(Wqh, Wql, Xh, QK_b, V_b, Qp, Kp, Vp);
  attn_mfma<<<dim3(1024, 6), dim3(256), 0, stream>>>(Qp, Kp, Vp, bias_tab, attnB);
  conv_gl<0><<<dim3(2048), dim3(256), 0, stream>>>(W1h, Vp, conv1_b, nullptr, T1r);
  conv_gl<1><<<dim3(2048), dim3(256), 0, stream>>>(W2h, T1r, conv2_b, attnB, S2r);
  proj_gemm<<<dim3(1024), dim3(256), 0, stream>>>(Wph, Wpl, S2r, proj_b, out);
}